// Round 4
// baseline (1329.282 us; speedup 1.0000x reference)
//
#include <hip/hip_runtime.h>
#include <cstdio>

// All float tensors are float32 (per reference). Edge arrays are int32.

// ---------- fills ----------
__global__ void zeroi_kernel(int* __restrict__ p, int n) {
    int i = blockIdx.x * blockDim.x + threadIdx.x;
    int stride = gridDim.x * blockDim.x;
    for (; i < n; i += stride) p[i] = 0;
}

// ---------- CSR build: histogram (INTEGER atomics only) ----------
__global__ void hist_kernel(const int* __restrict__ dst, int E, int* __restrict__ cnt, int Nd) {
    int i = blockIdx.x * blockDim.x + threadIdx.x;
    if (i >= E) return;
    int d = dst[i];
    if ((unsigned)d < (unsigned)Nd) atomicAdd(&cnt[d], 1);
}

// ---------- CSR build: one-block exclusive scan (Nd <= 16000) ----------
__global__ __launch_bounds__(1024)
void scan_kernel(const int* __restrict__ cnt, int* __restrict__ start, int Nd) {
    __shared__ int part[1024];
    int t = threadIdx.x;
    int k = (Nd + 1023) >> 10;
    int lo = t * k, hi = min(lo + k, Nd);
    if (lo > Nd) lo = Nd;
    int s = 0;
    for (int i = lo; i < hi; i++) s += cnt[i];
    part[t] = s;
    __syncthreads();
    for (int off = 1; off < 1024; off <<= 1) {
        int v = (t >= off) ? part[t - off] : 0;
        __syncthreads();
        part[t] += v;
        __syncthreads();
    }
    int run = (t > 0) ? part[t - 1] : 0;
    for (int i = lo; i < hi; i++) { start[i] = run; run += cnt[i]; }
    if (t == 1023) start[Nd] = part[1023];
}

// ---------- CSR build: fill (INTEGER atomics only, capacity-guarded) ----------
__global__ void fill_kernel(const int* __restrict__ src, const int* __restrict__ dst, int E,
                            const int* __restrict__ start, int* __restrict__ cursor,
                            int* __restrict__ csr_src, int Nd, int Ns) {
    int i = blockIdx.x * blockDim.x + threadIdx.x;
    if (i >= E) return;
    int d = dst[i];
    if ((unsigned)d >= (unsigned)Nd) return;
    int p = atomicAdd(&cursor[d], 1);
    int idx = start[d] + p;
    if (idx >= start[d + 1]) return;   // defensive (can't happen if hist/fill consistent)
    int s = src[i];
    if ((unsigned)s >= (unsigned)Ns) s = 0;
    csr_src[idx] = s;
}

// ---------- tiled GEMM: C[M,N] (fp32) = A[M,K] @ B[K,N], all row-major, all fp32 ----------
// requires M%64==0, N%64==0, K%16==0
#define BM 64
#define BN 64
#define BK 16

__global__ __launch_bounds__(256)
void gemm_kernel(const float* __restrict__ A, const float* __restrict__ B,
                 float* __restrict__ C, int M, int N, int K) {
    __shared__ float As[BK][BM + 1];
    __shared__ float Bs[BK][BN + 1];
    const int tid = threadIdx.x;
    const int tx = tid & 15, ty = tid >> 4;
    const int bm0 = blockIdx.y * BM, bn0 = blockIdx.x * BN;
    float acc[4][4] = {};
    for (int k0 = 0; k0 < K; k0 += BK) {
#pragma unroll
        for (int i = 0; i < 4; i++) {
            int ii = tid + i * 256;
            int am = ii >> 4, ak = ii & 15;
            As[ak][am] = A[(size_t)(bm0 + am) * K + (k0 + ak)];
            int bk = ii >> 6, bn = ii & 63;
            Bs[bk][bn] = B[(size_t)(k0 + bk) * N + (bn0 + bn)];
        }
        __syncthreads();
#pragma unroll
        for (int kk = 0; kk < BK; kk++) {
            float a[4], b[4];
#pragma unroll
            for (int i = 0; i < 4; i++) a[i] = As[kk][ty * 4 + i];
#pragma unroll
            for (int j = 0; j < 4; j++) b[j] = Bs[kk][tx * 4 + j];
#pragma unroll
            for (int i = 0; i < 4; i++)
#pragma unroll
                for (int j = 0; j < 4; j++)
                    acc[i][j] += a[i] * b[j];
        }
        __syncthreads();
    }
#pragma unroll
    for (int i = 0; i < 4; i++)
#pragma unroll
        for (int j = 0; j < 4; j++)
            C[(size_t)(bm0 + ty * 4 + i) * N + (bn0 + tx * 4 + j)] = acc[i][j];
}

// ---------- e[n,h] = sum_c h[n,h,c] * att[h,c] ----------
__global__ void escore_kernel(const float* __restrict__ h, const float* __restrict__ att,
                              float* __restrict__ e, int N, int H, int C) {
    int i = blockIdx.x * blockDim.x + threadIdx.x;
    if (i >= N * H) return;
    int n = i / H, hh = i - n * H;
    const float* hp = h + (size_t)n * H * C + hh * C;
    float s = 0.0f;
    for (int c = 0; c < C; c++) s += hp[c] * att[hh * C + c];
    e[i] = s;
}

// ---------- fused GAT aggregate: one wave per (dst node, head). NO atomics. ----------
// block = 64*H threads, grid = Nd. C == 64 (lane == channel in pass 3).
template <int H>
__global__ void gat_agg_kernel(const int* __restrict__ csr_src, const int* __restrict__ row_start,
                               const float* __restrict__ hs,   // [Ns,H,64]
                               const float* __restrict__ es,   // [Ns,H]
                               const float* __restrict__ ed,   // [Nd,H]
                               float* __restrict__ out,        // [Nd,H,64]
                               int Nd) {
    const int d = blockIdx.x;
    const int h = threadIdx.x >> 6;
    const int lane = threadIdx.x & 63;
    const int beg = row_start[d];
    const int deg = row_start[d + 1] - beg;
    const int n = deg + 1;                      // + self loop (i == deg -> s = d)
    const float edh = ed[(size_t)d * H + h];

    // pass 1: segment max of leaky_relu(es[s]+ed[d])
    float m = -1e30f;
    for (int i = lane; i < n; i += 64) {
        int s = (i < deg) ? csr_src[beg + i] : d;
        float a = es[(size_t)s * H + h] + edh;
        a = (a > 0.0f) ? a : 0.2f * a;
        m = fmaxf(m, a);
    }
#pragma unroll
    for (int off = 32; off; off >>= 1) m = fmaxf(m, __shfl_xor(m, off));

    // pass 2: denom = sum exp(a - m)  (>= 1: the max-achieving edge contributes 1)
    float ssum = 0.0f;
    for (int i = lane; i < n; i += 64) {
        int s = (i < deg) ? csr_src[beg + i] : d;
        float a = es[(size_t)s * H + h] + edh;
        a = (a > 0.0f) ? a : 0.2f * a;
        ssum += expf(a - m);
    }
#pragma unroll
    for (int off = 32; off; off >>= 1) ssum += __shfl_xor(ssum, off);
    const float inv = 1.0f / ssum;

    // pass 3: lane = channel; per-edge (w, s) broadcast via shfl; coalesced hs row reads
    float acc = 0.0f;
    for (int base = 0; base < n; base += 64) {
        int i = base + lane;
        int s = d;
        float w = 0.0f;
        if (i < n) {
            s = (i < deg) ? csr_src[beg + i] : d;
            float a = es[(size_t)s * H + h] + edh;
            a = (a > 0.0f) ? a : 0.2f * a;
            w = expf(a - m) * inv;
        }
        int cnt = min(64, n - base);
        for (int j = 0; j < cnt; j++) {
            int sj = __shfl(s, j);
            float wj = __shfl(w, j);
            acc += wj * hs[(size_t)sj * (H * 64) + h * 64 + lane];
        }
    }
    out[(size_t)d * (H * 64) + h * 64 + lane] = acc;
}

// ---------- in-place bias + ELU ----------
__global__ void bias_elu_kernel(float* __restrict__ acc, const float* __restrict__ bias,
                                int N, int D) {
    int i = blockIdx.x * blockDim.x + threadIdx.x;
    if (i >= N * D) return;
    int d = i % D;
    float v = acc[i] + bias[d];
    acc[i] = (v > 0.0f) ? v : expm1f(v);
}

// ---------- final: head-mean + bias2, concat with (flat@W+b) and last, 192-dot ----------
__global__ void final_kernel(const float* __restrict__ acc2, const float* __restrict__ bias2,
                             const float* __restrict__ fbuf, const float* __restrict__ flat_b,
                             const float* __restrict__ last, const float* __restrict__ outW,
                             const float* __restrict__ outb, float* __restrict__ out, int N) {
    int n = blockIdx.x * blockDim.x + threadIdx.x;
    if (n >= N) return;
    float s = outb[0];
    const float* a = acc2 + (size_t)n * 256;
    for (int c = 0; c < 64; c++) {
        float h2 = 0.25f * (a[c] + a[64 + c] + a[128 + c] + a[192 + c]) + bias2[c];
        s += h2 * outW[c];
        s += (fbuf[(size_t)n * 64 + c] + flat_b[c]) * outW[64 + c];
        s += last[(size_t)n * 64 + c] * outW[128 + c];
    }
    out[n] = s;
}

// ---------- graph/model dims ----------
#define N1 80000
#define N2 16000
#define N3 4096
#define E1 256000
#define E2 65536

extern "C" void kernel_launch(void* const* d_in, const int* in_sizes, int n_in,
                              void* d_out, int out_size, void* d_ws, size_t ws_size,
                              hipStream_t stream) {
    const float* x    = (const float*)d_in[0];
    const float* flat = (const float*)d_in[1];
    const float* last = (const float*)d_in[2];
    const int*  es1i  = (const int*)d_in[3];
    const int*  ed1i  = (const int*)d_in[4];
    const int*  es2i  = (const int*)d_in[5];
    const int*  ed2i  = (const int*)d_in[6];
    const float* W1s  = (const float*)d_in[7];
    const float* W1d  = (const float*)d_in[8];
    const float* a1s  = (const float*)d_in[9];
    const float* a1d  = (const float*)d_in[10];
    const float* b1   = (const float*)d_in[11];
    const float* W2s  = (const float*)d_in[12];
    const float* W2d  = (const float*)d_in[13];
    const float* a2s  = (const float*)d_in[14];
    const float* a2d  = (const float*)d_in[15];
    const float* b2   = (const float*)d_in[16];
    const float* fW   = (const float*)d_in[17];
    const float* fb   = (const float*)d_in[18];
    const float* oW   = (const float*)d_in[19];
    const float* ob   = (const float*)d_in[20];
    float* out = (float*)d_out;

    float* ws = (float*)d_ws;
    // ---- float workspace layout (element offsets) ----
    float* hs1  = ws;                       // 80000*512 = 40,960,000
    float* hd1  = ws + 40960000;            // 16000*512 =  8,192,000
    float* es1f = ws + 49152000;            //    640,000
    float* ed1f = ws + 49792000;            //    128,000
    float* acc1 = ws + 49920000;            //  8,192,000  -> ends 58,112,000
    // ---- int workspace region ----
    int* ibase   = (int*)(ws + 58112000);
    int* cnt1    = ibase;                   // 16,000
    int* start1  = ibase + 16000;           // 16,001
    int* cursor1 = ibase + 32001;           // 16,000
    int* csr1    = ibase + 48001;           // 256,000
    int* cnt2    = ibase + 304001;          // 4,096
    int* start2  = ibase + 308097;          // 4,097
    int* cursor2 = ibase + 312194;          // 4,096
    int* csr2    = ibase + 316290;          // 65,536 -> iend 381,826
    const size_t NEED = ((size_t)58112000 + 381826) * 4;
    if (ws_size < NEED) {
        fprintf(stderr, "kernel_launch: ws_size %zu < needed %zu\n", ws_size, NEED);
        return;
    }
    // ---- layer-2 buffers alias hs1 region (dead after layer-1 aggregate) ----
    float* hs2  = ws;                       // 16000*256 = 4,096,000
    float* hd2  = ws + 4096000;             //  4096*256 = 1,048,576
    float* es2f = ws + 5144576;             //     64,000
    float* ed2f = ws + 5208576;             //     16,384
    float* acc2 = ws + 5224960;             //  1,048,576
    float* fbuf = ws + 6273536;             //    262,144 -> ends 6,535,680

    // ---- CSR build (integer atomics only) ----
    zeroi_kernel<<<64, 256, 0, stream>>>(cnt1, 16000);
    zeroi_kernel<<<64, 256, 0, stream>>>(cursor1, 16000);
    zeroi_kernel<<<16, 256, 0, stream>>>(cnt2, 4096);
    zeroi_kernel<<<16, 256, 0, stream>>>(cursor2, 4096);
    hist_kernel<<<(E1 + 255) / 256, 256, 0, stream>>>(ed1i, E1, cnt1, N2);
    scan_kernel<<<1, 1024, 0, stream>>>(cnt1, start1, N2);
    fill_kernel<<<(E1 + 255) / 256, 256, 0, stream>>>(es1i, ed1i, E1, start1, cursor1, csr1, N2, N1);
    hist_kernel<<<(E2 + 255) / 256, 256, 0, stream>>>(ed2i, E2, cnt2, N3);
    scan_kernel<<<1, 1024, 0, stream>>>(cnt2, start2, N3);
    fill_kernel<<<(E2 + 255) / 256, 256, 0, stream>>>(es2i, ed2i, E2, start2, cursor2, csr2, N3, N2);

    // ---- layer 1 ----
    gemm_kernel<<<dim3(512 / BN, N1 / BM), 256, 0, stream>>>(x, W1s, hs1, N1, 512, 256);
    gemm_kernel<<<dim3(512 / BN, N2 / BM), 256, 0, stream>>>(x, W1d, hd1, N2, 512, 256);
    escore_kernel<<<(N1 * 8 + 255) / 256, 256, 0, stream>>>(hs1, a1s, es1f, N1, 8, 64);
    escore_kernel<<<(N2 * 8 + 255) / 256, 256, 0, stream>>>(hd1, a1d, ed1f, N2, 8, 64);
    gat_agg_kernel<8><<<N2, 512, 0, stream>>>(csr1, start1, hs1, es1f, ed1f, acc1, N2);
    bias_elu_kernel<<<(N2 * 512 + 255) / 256, 256, 0, stream>>>(acc1, b1, N2, 512);

    // ---- layer 2 ----
    gemm_kernel<<<dim3(256 / BN, N2 / BM), 256, 0, stream>>>(acc1, W2s, hs2, N2, 256, 512);
    gemm_kernel<<<dim3(256 / BN, N3 / BM), 256, 0, stream>>>(acc1, W2d, hd2, N3, 256, 512);
    escore_kernel<<<(N2 * 4 + 255) / 256, 256, 0, stream>>>(hs2, a2s, es2f, N2, 4, 64);
    escore_kernel<<<(N3 * 4 + 255) / 256, 256, 0, stream>>>(hd2, a2d, ed2f, N3, 4, 64);
    gat_agg_kernel<4><<<N3, 256, 0, stream>>>(csr2, start2, hs2, es2f, ed2f, acc2, N3);

    // ---- flat MLP + output ----
    gemm_kernel<<<dim3(64 / BN, N3 / BM), 256, 0, stream>>>(flat, fW, fbuf, N3, 64, 128);
    final_kernel<<<(N3 + 255) / 256, 256, 0, stream>>>(acc2, b2, fbuf, fb, last, oW, ob, out, N3);
}

// Round 5
// 787.245 us; speedup vs baseline: 1.6885x; 1.6885x over previous
//
#include <hip/hip_runtime.h>
#include <hip/hip_bf16.h>
#include <cstdio>

typedef __attribute__((ext_vector_type(8))) short short8;
typedef __attribute__((ext_vector_type(4))) float f32x4;

// ---------- bf16 helpers ----------
__device__ __forceinline__ float bfu2f(unsigned short u) {
    return __uint_as_float(((unsigned)u) << 16);
}
__device__ __forceinline__ unsigned short f2bfu(float f) {   // RNE via HIP intrinsic
    __hip_bfloat16 b = __float2bfloat16(f);
    union { __hip_bfloat16 b; unsigned short u; } cv; cv.b = b;
    return cv.u;
}
__device__ __forceinline__ void store_out(float* p, float v) { *p = v; }
__device__ __forceinline__ void store_out(unsigned short* p, float v) { *p = f2bfu(v); }

// ---------- fills ----------
__global__ void zeroi_kernel(int* __restrict__ p, int n) {
    int i = blockIdx.x * blockDim.x + threadIdx.x;
    int stride = gridDim.x * blockDim.x;
    for (; i < n; i += stride) p[i] = 0;
}

// ---------- CSR build ----------
__global__ void hist_kernel(const int* __restrict__ dst, int E, int* __restrict__ cnt, int Nd) {
    int i = blockIdx.x * blockDim.x + threadIdx.x;
    if (i >= E) return;
    int d = dst[i];
    if ((unsigned)d < (unsigned)Nd) atomicAdd(&cnt[d], 1);
}
__global__ __launch_bounds__(1024)
void scan_kernel(const int* __restrict__ cnt, int* __restrict__ start, int Nd) {
    __shared__ int part[1024];
    int t = threadIdx.x;
    int k = (Nd + 1023) >> 10;
    int lo = t * k, hi = min(lo + k, Nd);
    if (lo > Nd) lo = Nd;
    int s = 0;
    for (int i = lo; i < hi; i++) s += cnt[i];
    part[t] = s;
    __syncthreads();
    for (int off = 1; off < 1024; off <<= 1) {
        int v = (t >= off) ? part[t - off] : 0;
        __syncthreads();
        part[t] += v;
        __syncthreads();
    }
    int run = (t > 0) ? part[t - 1] : 0;
    for (int i = lo; i < hi; i++) { start[i] = run; run += cnt[i]; }
    if (t == 1023) start[Nd] = part[1023];
}
__global__ void fill_kernel(const int* __restrict__ src, const int* __restrict__ dst, int E,
                            const int* __restrict__ start, int* __restrict__ cursor,
                            int* __restrict__ csr_src, int Nd, int Ns) {
    int i = blockIdx.x * blockDim.x + threadIdx.x;
    if (i >= E) return;
    int d = dst[i];
    if ((unsigned)d >= (unsigned)Nd) return;
    int p = atomicAdd(&cursor[d], 1);
    int idx = start[d] + p;
    if (idx >= start[d + 1]) return;
    int s = src[i];
    if ((unsigned)s >= (unsigned)Ns) s = 0;
    csr_src[idx] = s;
}

// ---------- fp32 -> (bf16 hi, bf16 lo) elementwise split ----------
__global__ void split_kernel(const float* __restrict__ X, unsigned short* __restrict__ hi,
                             unsigned short* __restrict__ lo, size_t n) {
    size_t i = (size_t)blockIdx.x * blockDim.x + threadIdx.x;
    size_t stride = (size_t)gridDim.x * blockDim.x;
    for (; i < n; i += stride) {
        float v = X[i];
        unsigned short h = f2bfu(v);
        hi[i] = h;
        lo[i] = f2bfu(v - bfu2f(h));
    }
}

// ---------- W [K][N] fp32 -> Bt3 [N][3K] bf16 = [hi | lo | hi] along k ----------
__global__ void wsplit_kernel(const float* __restrict__ W, unsigned short* __restrict__ Bt3,
                              int K, int N) {
    int i = blockIdx.x * blockDim.x + threadIdx.x;
    if (i >= K * N) return;
    int k = i / N, n = i - k * N;
    float v = W[(size_t)k * N + n];
    unsigned short h = f2bfu(v);
    unsigned short l = f2bfu(v - bfu2f(h));
    size_t base = (size_t)n * (3 * K);
    Bt3[base + k] = h;
    Bt3[base + K + k] = l;
    Bt3[base + 2 * K + k] = h;
}

// ---------- MFMA GEMM: C[M,N] = A[M,K] @ B[K,N] via bf16x3 split ----------
// A given as (Ahi, Alo) [M][K]; B given materialized as Bt3 [N][3K] (k-contiguous).
// Segments of KK=3K: seg0 -> Ahi*Bt3(hi), seg1 -> Ahi*Bt3(lo), seg2 -> Alo*Bt3(hi).
// Requires M%64==0, N%64==0, K%64==0.
template <typename OutT>
__global__ __launch_bounds__(256)
void gemm_mfma(const unsigned short* __restrict__ Ahi, const unsigned short* __restrict__ Alo,
               const unsigned short* __restrict__ Bt3, OutT* __restrict__ C,
               int M, int N, int K) {
    const int KK = 3 * K;
    __shared__ unsigned short As[64][72];   // +8 pad: conflict-light b128 frag reads
    __shared__ unsigned short Bs[64][72];
    const int tid = threadIdx.x;
    const int wave = tid >> 6, lane = tid & 63;
    const int wr = wave >> 1, wc = wave & 1;
    const int quad = lane >> 4, l15 = lane & 15;
    const int m0 = blockIdx.y * 64, n0 = blockIdx.x * 64;
    f32x4 acc[2][2] = {};
    for (int k0 = 0; k0 < KK; k0 += 64) {
        const int seg = k0 / K;
        const int ks = k0 - seg * K;
        const unsigned short* Asrc = (seg < 2) ? Ahi : Alo;
#pragma unroll
        for (int i = 0; i < 2; i++) {
            int idx = tid + i * 256;            // 0..511
            int r = idx >> 3, cv = (idx & 7) * 8;
            *(short8*)&As[r][cv] = *(const short8*)&Asrc[(size_t)(m0 + r) * K + ks + cv];
            *(short8*)&Bs[r][cv] = *(const short8*)&Bt3[(size_t)(n0 + r) * KK + k0 + cv];
        }
        __syncthreads();
#pragma unroll
        for (int kk = 0; kk < 64; kk += 32) {
            short8 a[2], b[2];
#pragma unroll
            for (int t = 0; t < 2; t++) {
                a[t] = *(const short8*)&As[wr * 32 + t * 16 + l15][kk + quad * 8];
                b[t] = *(const short8*)&Bs[wc * 32 + t * 16 + l15][kk + quad * 8];
            }
#pragma unroll
            for (int mt = 0; mt < 2; mt++)
#pragma unroll
                for (int nt = 0; nt < 2; nt++)
                    acc[mt][nt] = __builtin_amdgcn_mfma_f32_16x16x32_bf16(
                        a[mt], b[nt], acc[mt][nt], 0, 0, 0);
        }
        __syncthreads();
    }
#pragma unroll
    for (int mt = 0; mt < 2; mt++)
#pragma unroll
        for (int nt = 0; nt < 2; nt++)
#pragma unroll
            for (int r = 0; r < 4; r++) {
                int row = m0 + wr * 32 + mt * 16 + quad * 4 + r;
                int col = n0 + wc * 32 + nt * 16 + l15;
                store_out(&C[(size_t)row * N + col], acc[mt][nt][r]);
            }
}

// ---------- e[n,h] = sum_c h_bf[n,h,c] * att[h,c], C=64 ----------
__global__ void escore_kernel(const unsigned short* __restrict__ h, const float* __restrict__ att,
                              float* __restrict__ e, int N, int H) {
    int i = blockIdx.x * blockDim.x + threadIdx.x;
    if (i >= N * H) return;
    int n = i / H, hh = i - n * H;
    const unsigned short* hp = h + (size_t)n * H * 64 + hh * 64;
    const float* ap = att + hh * 64;
    float s = 0.0f;
    for (int c = 0; c < 64; c++) s += bfu2f(hp[c]) * ap[c];
    e[i] = s;
}

// ---------- fused GAT aggregate (bf16 h gather, optional bias+ELU epilogue) ----------
template <int H, bool ELU>
__global__ void gat_agg_kernel(const int* __restrict__ csr_src, const int* __restrict__ row_start,
                               const unsigned short* __restrict__ hs,  // [Ns,H,64] bf16
                               const float* __restrict__ es,           // [Ns,H]
                               const float* __restrict__ ed,           // [Nd,H]
                               const float* __restrict__ bias,         // [H*64] or null
                               float* __restrict__ out,                // [Nd,H,64] fp32
                               int Nd) {
    const int d = blockIdx.x;
    const int h = threadIdx.x >> 6;
    const int lane = threadIdx.x & 63;
    const int beg = row_start[d];
    const int deg = row_start[d + 1] - beg;
    const int n = deg + 1;
    const float edh = ed[(size_t)d * H + h];

    float m = -1e30f;
    for (int i = lane; i < n; i += 64) {
        int s = (i < deg) ? csr_src[beg + i] : d;
        float a = es[(size_t)s * H + h] + edh;
        a = (a > 0.0f) ? a : 0.2f * a;
        m = fmaxf(m, a);
    }
#pragma unroll
    for (int off = 32; off; off >>= 1) m = fmaxf(m, __shfl_xor(m, off));

    float ssum = 0.0f;
    for (int i = lane; i < n; i += 64) {
        int s = (i < deg) ? csr_src[beg + i] : d;
        float a = es[(size_t)s * H + h] + edh;
        a = (a > 0.0f) ? a : 0.2f * a;
        ssum += expf(a - m);
    }
#pragma unroll
    for (int off = 32; off; off >>= 1) ssum += __shfl_xor(ssum, off);
    const float inv = 1.0f / ssum;

    float acc = 0.0f;
    for (int base = 0; base < n; base += 64) {
        int i = base + lane;
        int s = d;
        float w = 0.0f;
        if (i < n) {
            s = (i < deg) ? csr_src[beg + i] : d;
            float a = es[(size_t)s * H + h] + edh;
            a = (a > 0.0f) ? a : 0.2f * a;
            w = expf(a - m) * inv;
        }
        int cnt = min(64, n - base);
        for (int j = 0; j < cnt; j++) {
            int sj = __shfl(s, j);
            float wj = __shfl(w, j);
            acc += wj * bfu2f(hs[(size_t)sj * (H * 64) + h * 64 + lane]);
        }
    }
    if (ELU) {
        float v = acc + bias[h * 64 + lane];
        acc = (v > 0.0f) ? v : expm1f(v);
    }
    out[(size_t)d * (H * 64) + h * 64 + lane] = acc;
}

// ---------- final: head-mean + bias2, concat with (flat@W+b) and last, 192-dot ----------
__global__ void final_kernel(const float* __restrict__ acc2, const float* __restrict__ bias2,
                             const float* __restrict__ fbuf, const float* __restrict__ flat_b,
                             const float* __restrict__ last, const float* __restrict__ outW,
                             const float* __restrict__ outb, float* __restrict__ out, int N) {
    int n = blockIdx.x * blockDim.x + threadIdx.x;
    if (n >= N) return;
    float s = outb[0];
    const float* a = acc2 + (size_t)n * 256;
    for (int c = 0; c < 64; c++) {
        float h2 = 0.25f * (a[c] + a[64 + c] + a[128 + c] + a[192 + c]) + bias2[c];
        s += h2 * outW[c];
        s += (fbuf[(size_t)n * 64 + c] + flat_b[c]) * outW[64 + c];
        s += last[(size_t)n * 64 + c] * outW[128 + c];
    }
    out[n] = s;
}

// ---------- graph/model dims ----------
#define N1 80000
#define N2 16000
#define N3 4096
#define E1 256000
#define E2 65536

extern "C" void kernel_launch(void* const* d_in, const int* in_sizes, int n_in,
                              void* d_out, int out_size, void* d_ws, size_t ws_size,
                              hipStream_t stream) {
    const float* x    = (const float*)d_in[0];
    const float* flat = (const float*)d_in[1];
    const float* last = (const float*)d_in[2];
    const int*  es1i  = (const int*)d_in[3];
    const int*  ed1i  = (const int*)d_in[4];
    const int*  es2i  = (const int*)d_in[5];
    const int*  ed2i  = (const int*)d_in[6];
    const float* W1s  = (const float*)d_in[7];
    const float* W1d  = (const float*)d_in[8];
    const float* a1s  = (const float*)d_in[9];
    const float* a1d  = (const float*)d_in[10];
    const float* b1   = (const float*)d_in[11];
    const float* W2s  = (const float*)d_in[12];
    const float* W2d  = (const float*)d_in[13];
    const float* a2s  = (const float*)d_in[14];
    const float* a2d  = (const float*)d_in[15];
    const float* b2   = (const float*)d_in[16];
    const float* fW   = (const float*)d_in[17];
    const float* fb   = (const float*)d_in[18];
    const float* oW   = (const float*)d_in[19];
    const float* ob   = (const float*)d_in[20];
    float* out = (float*)d_out;

    float* ws = (float*)d_ws;
    // ---- layout (float-element offsets) ----
    unsigned short* hs1_bf = (unsigned short*)ws;                  // 40,960,000 us = fl[0 .. 20,480,000)
    unsigned short* hd1_bf = (unsigned short*)(ws + 20480000);     //  8,192,000 us -> fl 24,576,000
    float* es1f = ws + 24576000;                                   // 640,000
    float* ed1f = ws + 25216000;                                   // 128,000
    float* acc1 = ws + 25344000;                                   // 8,192,000 -> 33,536,000
    // R1 (phase A): x split, dead after layer-1 GEMMs
    unsigned short* x_hi = (unsigned short*)(ws + 33536000);       // 20,480,000 us
    unsigned short* x_lo = (unsigned short*)(ws + 43776000);       // 20,480,000 us -> fl 54,016,000
    // R1 (phase B): acc1 split + flat split (alias x region)
    unsigned short* a2_hi = (unsigned short*)(ws + 33536000);      // 8,192,000 us
    unsigned short* a2_lo = (unsigned short*)(ws + 37632000);      // 8,192,000 us
    unsigned short* f_hi  = (unsigned short*)(ws + 41728000);      // 524,288 us
    unsigned short* f_lo  = (unsigned short*)(ws + 41990144);      // 524,288 us
    // weights (bf16x3, transposed): [54,016,000 .. 54,816,000)
    unsigned short* wbase = (unsigned short*)(ws + 54016000);
    unsigned short* w1s_t3 = wbase;                                // 512*768 = 393,216
    unsigned short* w1d_t3 = wbase + 393216;
    unsigned short* w2s_t3 = wbase + 786432;                       // 256*1536
    unsigned short* w2d_t3 = wbase + 1179648;
    unsigned short* fw_t3  = wbase + 1572864;                      // 64*384 -> 1,597,440 us
    // ints
    int* ibase   = (int*)(ws + 54816000);
    int* cnt1    = ibase;
    int* start1  = ibase + 16000;
    int* cursor1 = ibase + 32001;
    int* csr1    = ibase + 48001;
    int* cnt2    = ibase + 304001;
    int* start2  = ibase + 308097;
    int* cursor2 = ibase + 312194;
    int* csr2    = ibase + 316290;                                 // -> 381,826 ints
    const size_t NEED = ((size_t)54816000 + 381826) * 4;
    if (ws_size < NEED) {
        fprintf(stderr, "kernel_launch: ws_size %zu < needed %zu\n", ws_size, NEED);
        return;
    }
    // layer-2 aliases inside dead hs1_bf region (all < fl 20,480,000)
    unsigned short* hs2_bf = (unsigned short*)ws;                  // 4,096,000 us
    unsigned short* hd2_bf = (unsigned short*)(ws + 2048000);      // 1,048,576 us
    float* es2f = ws + 2572288;                                    // 64,000
    float* ed2f = ws + 2636288;                                    // 16,384
    float* acc2 = ws + 2652672;                                    // 1,048,576
    float* fbuf = ws + 3701248;                                    // 262,144

    // ---- prep: splits + CSR (independent) ----
    split_kernel<<<4096, 256, 0, stream>>>(x, x_hi, x_lo, (size_t)N1 * 256);
    wsplit_kernel<<<(256 * 512 + 255) / 256, 256, 0, stream>>>(W1s, w1s_t3, 256, 512);
    wsplit_kernel<<<(256 * 512 + 255) / 256, 256, 0, stream>>>(W1d, w1d_t3, 256, 512);
    wsplit_kernel<<<(512 * 256 + 255) / 256, 256, 0, stream>>>(W2s, w2s_t3, 512, 256);
    wsplit_kernel<<<(512 * 256 + 255) / 256, 256, 0, stream>>>(W2d, w2d_t3, 512, 256);
    wsplit_kernel<<<(128 * 64 + 255) / 256, 256, 0, stream>>>(fW, fw_t3, 128, 64);
    zeroi_kernel<<<64, 256, 0, stream>>>(cnt1, 16000);
    zeroi_kernel<<<64, 256, 0, stream>>>(cursor1, 16000);
    zeroi_kernel<<<16, 256, 0, stream>>>(cnt2, 4096);
    zeroi_kernel<<<16, 256, 0, stream>>>(cursor2, 4096);
    hist_kernel<<<(E1 + 255) / 256, 256, 0, stream>>>(ed1i, E1, cnt1, N2);
    scan_kernel<<<1, 1024, 0, stream>>>(cnt1, start1, N2);
    fill_kernel<<<(E1 + 255) / 256, 256, 0, stream>>>(es1i, ed1i, E1, start1, cursor1, csr1, N2, N1);
    hist_kernel<<<(E2 + 255) / 256, 256, 0, stream>>>(ed2i, E2, cnt2, N3);
    scan_kernel<<<1, 1024, 0, stream>>>(cnt2, start2, N3);
    fill_kernel<<<(E2 + 255) / 256, 256, 0, stream>>>(es2i, ed2i, E2, start2, cursor2, csr2, N3, N2);

    // ---- layer 1: h = x @ W (bf16x3 MFMA), bf16 out ----
    gemm_mfma<unsigned short><<<dim3(512 / 64, N1 / 64), 256, 0, stream>>>(
        x_hi, x_lo, w1s_t3, hs1_bf, N1, 512, 256);
    gemm_mfma<unsigned short><<<dim3(512 / 64, N2 / 64), 256, 0, stream>>>(
        x_hi, x_lo, w1d_t3, hd1_bf, N2, 512, 256);
    escore_kernel<<<(N1 * 8 + 255) / 256, 256, 0, stream>>>(hs1_bf, a1s, es1f, N1, 8);
    escore_kernel<<<(N2 * 8 + 255) / 256, 256, 0, stream>>>(hd1_bf, a1d, ed1f, N2, 8);
    gat_agg_kernel<8, true><<<N2, 512, 0, stream>>>(csr1, start1, hs1_bf, es1f, ed1f, b1, acc1, N2);

    // ---- layer 2 ----
    split_kernel<<<4096, 256, 0, stream>>>(acc1, a2_hi, a2_lo, (size_t)N2 * 512);
    gemm_mfma<unsigned short><<<dim3(256 / 64, N2 / 64), 256, 0, stream>>>(
        a2_hi, a2_lo, w2s_t3, hs2_bf, N2, 256, 512);
    gemm_mfma<unsigned short><<<dim3(256 / 64, N3 / 64), 256, 0, stream>>>(
        a2_hi, a2_lo, w2d_t3, hd2_bf, N3, 256, 512);
    escore_kernel<<<(N2 * 4 + 255) / 256, 256, 0, stream>>>(hs2_bf, a2s, es2f, N2, 4);
    escore_kernel<<<(N3 * 4 + 255) / 256, 256, 0, stream>>>(hd2_bf, a2d, ed2f, N3, 4);
    gat_agg_kernel<4, false><<<N3, 256, 0, stream>>>(csr2, start2, hs2_bf, es2f, ed2f, nullptr, acc2, N3);

    // ---- flat MLP + output ----
    split_kernel<<<2048, 256, 0, stream>>>(flat, f_hi, f_lo, (size_t)N3 * 128);
    gemm_mfma<float><<<dim3(64 / 64, N3 / 64), 256, 0, stream>>>(
        f_hi, f_lo, fw_t3, fbuf, N3, 64, 128);
    final_kernel<<<(N3 + 255) / 256, 256, 0, stream>>>(acc2, b2, fbuf, fb, last, oW, ob, out, N3);
}

// Round 6
// 709.998 us; speedup vs baseline: 1.8722x; 1.1088x over previous
//
#include <hip/hip_runtime.h>
#include <hip/hip_bf16.h>
#include <cstdio>

typedef __attribute__((ext_vector_type(8))) short short8;
typedef __attribute__((ext_vector_type(4))) float f32x4;

// ---------- bf16 helpers ----------
__device__ __forceinline__ float bfu2f(unsigned short u) {
    return __uint_as_float(((unsigned)u) << 16);
}
__device__ __forceinline__ unsigned short f2bfu(float f) {   // RNE via HIP intrinsic
    __hip_bfloat16 b = __float2bfloat16(f);
    union { __hip_bfloat16 b; unsigned short u; } cv; cv.b = b;
    return cv.u;
}
__device__ __forceinline__ void store_out(float* p, float v) { *p = v; }
__device__ __forceinline__ void store_out(unsigned short* p, float v) { *p = f2bfu(v); }

// ---------- fills ----------
__global__ void zeroi_kernel(int* __restrict__ p, int n) {
    int i = blockIdx.x * blockDim.x + threadIdx.x;
    int stride = gridDim.x * blockDim.x;
    for (; i < n; i += stride) p[i] = 0;
}

// ---------- CSR build ----------
__global__ void hist_kernel(const int* __restrict__ dst, int E, int* __restrict__ cnt, int Nd) {
    int i = blockIdx.x * blockDim.x + threadIdx.x;
    if (i >= E) return;
    int d = dst[i];
    if ((unsigned)d < (unsigned)Nd) atomicAdd(&cnt[d], 1);
}
__global__ __launch_bounds__(1024)
void scan_kernel(const int* __restrict__ cnt, int* __restrict__ start, int Nd) {
    __shared__ int part[1024];
    int t = threadIdx.x;
    int k = (Nd + 1023) >> 10;
    int lo = t * k, hi = min(lo + k, Nd);
    if (lo > Nd) lo = Nd;
    int s = 0;
    for (int i = lo; i < hi; i++) s += cnt[i];
    part[t] = s;
    __syncthreads();
    for (int off = 1; off < 1024; off <<= 1) {
        int v = (t >= off) ? part[t - off] : 0;
        __syncthreads();
        part[t] += v;
        __syncthreads();
    }
    int run = (t > 0) ? part[t - 1] : 0;
    for (int i = lo; i < hi; i++) { start[i] = run; run += cnt[i]; }
    if (t == 1023) start[Nd] = part[1023];
}
__global__ void fill_kernel(const int* __restrict__ src, const int* __restrict__ dst, int E,
                            const int* __restrict__ start, int* __restrict__ cursor,
                            int* __restrict__ csr_src, int Nd, int Ns) {
    int i = blockIdx.x * blockDim.x + threadIdx.x;
    if (i >= E) return;
    int d = dst[i];
    if ((unsigned)d >= (unsigned)Nd) return;
    int p = atomicAdd(&cursor[d], 1);
    int idx = start[d] + p;
    if (idx >= start[d + 1]) return;
    int s = src[i];
    if ((unsigned)s >= (unsigned)Ns) s = 0;
    csr_src[idx] = s;
}

// ---------- fp32 -> (bf16 hi, bf16 lo) elementwise split ----------
__global__ void split_kernel(const float* __restrict__ X, unsigned short* __restrict__ hi,
                             unsigned short* __restrict__ lo, size_t n) {
    size_t i = (size_t)blockIdx.x * blockDim.x + threadIdx.x;
    size_t stride = (size_t)gridDim.x * blockDim.x;
    for (; i < n; i += stride) {
        float v = X[i];
        unsigned short h = f2bfu(v);
        hi[i] = h;
        lo[i] = f2bfu(v - bfu2f(h));
    }
}

// ---------- W [K][N] fp32 -> Bt3 [N][3K] bf16 = [hi | lo | hi] along k ----------
__global__ void wsplit_kernel(const float* __restrict__ W, unsigned short* __restrict__ Bt3,
                              int K, int N) {
    int i = blockIdx.x * blockDim.x + threadIdx.x;
    if (i >= K * N) return;
    int k = i / N, n = i - k * N;
    float v = W[(size_t)k * N + n];
    unsigned short h = f2bfu(v);
    unsigned short l = f2bfu(v - bfu2f(h));
    size_t base = (size_t)n * (3 * K);
    Bt3[base + k] = h;
    Bt3[base + K + k] = l;
    Bt3[base + 2 * K + k] = h;
}

// ---------- MFMA GEMM: C[M,N] = A[M,K] @ B[K,N] via bf16x3 split ----------
template <typename OutT>
__global__ __launch_bounds__(256)
void gemm_mfma(const unsigned short* __restrict__ Ahi, const unsigned short* __restrict__ Alo,
               const unsigned short* __restrict__ Bt3, OutT* __restrict__ C,
               int M, int N, int K) {
    const int KK = 3 * K;
    __shared__ unsigned short As[64][72];
    __shared__ unsigned short Bs[64][72];
    const int tid = threadIdx.x;
    const int wave = tid >> 6, lane = tid & 63;
    const int wr = wave >> 1, wc = wave & 1;
    const int quad = lane >> 4, l15 = lane & 15;
    const int m0 = blockIdx.y * 64, n0 = blockIdx.x * 64;
    f32x4 acc[2][2] = {};
    for (int k0 = 0; k0 < KK; k0 += 64) {
        const int seg = k0 / K;
        const int ks = k0 - seg * K;
        const unsigned short* Asrc = (seg < 2) ? Ahi : Alo;
#pragma unroll
        for (int i = 0; i < 2; i++) {
            int idx = tid + i * 256;
            int r = idx >> 3, cv = (idx & 7) * 8;
            *(short8*)&As[r][cv] = *(const short8*)&Asrc[(size_t)(m0 + r) * K + ks + cv];
            *(short8*)&Bs[r][cv] = *(const short8*)&Bt3[(size_t)(n0 + r) * KK + k0 + cv];
        }
        __syncthreads();
#pragma unroll
        for (int kk = 0; kk < 64; kk += 32) {
            short8 a[2], b[2];
#pragma unroll
            for (int t = 0; t < 2; t++) {
                a[t] = *(const short8*)&As[wr * 32 + t * 16 + l15][kk + quad * 8];
                b[t] = *(const short8*)&Bs[wc * 32 + t * 16 + l15][kk + quad * 8];
            }
#pragma unroll
            for (int mt = 0; mt < 2; mt++)
#pragma unroll
                for (int nt = 0; nt < 2; nt++)
                    acc[mt][nt] = __builtin_amdgcn_mfma_f32_16x16x32_bf16(
                        a[mt], b[nt], acc[mt][nt], 0, 0, 0);
        }
        __syncthreads();
    }
#pragma unroll
    for (int mt = 0; mt < 2; mt++)
#pragma unroll
        for (int nt = 0; nt < 2; nt++)
#pragma unroll
            for (int r = 0; r < 4; r++) {
                int row = m0 + wr * 32 + mt * 16 + quad * 4 + r;
                int col = n0 + wc * 32 + nt * 16 + l15;
                store_out(&C[(size_t)row * N + col], acc[mt][nt][r]);
            }
}

// ---------- e[n,h] = sum_c h_bf[n,h,c] * att[h,c], C=64 ----------
__global__ void escore_kernel(const unsigned short* __restrict__ h, const float* __restrict__ att,
                              float* __restrict__ e, int N, int H) {
    int i = blockIdx.x * blockDim.x + threadIdx.x;
    if (i >= N * H) return;
    int n = i / H, hh = i - n * H;
    const unsigned short* hp = h + (size_t)n * H * 64 + hh * 64;
    const float* ap = att + hh * 64;
    float s = 0.0f;
    for (int c = 0; c < 64; c++) s += bfu2f(hp[c]) * ap[c];
    e[i] = s;
}

// ---------- fused GAT aggregate: one wave per (dst, head); register fast-path + ILP-8 gather ----------
template <int H, bool ELU>
__global__ void gat_agg_kernel(const int* __restrict__ csr_src, const int* __restrict__ row_start,
                               const unsigned short* __restrict__ hs,  // [Ns,H,64] bf16
                               const float* __restrict__ es,           // [Ns,H]
                               const float* __restrict__ ed,           // [Nd,H]
                               const float* __restrict__ bias,         // [H*64] or null
                               float* __restrict__ out,                // [Nd,H,64] fp32
                               int Nd) {
    const int d = blockIdx.x;
    const int h = threadIdx.x >> 6;
    const int lane = threadIdx.x & 63;
    const int beg = row_start[d];
    const int deg = row_start[d + 1] - beg;
    const int n = deg + 1;                 // + self loop
    const float edh = ed[(size_t)d * H + h];
    const size_t hbase = (size_t)h * 64 + lane;
    float acc = 0.0f;

    if (n <= 64) {
        // ---- register fast-path: one edge per lane; single es gather ----
        const bool valid = lane < n;
        int s_reg = d;
        float a_reg = -1e30f;
        if (valid) {
            s_reg = (lane < deg) ? csr_src[beg + lane] : d;
            float a = es[(size_t)s_reg * H + h] + edh;
            a_reg = (a > 0.0f) ? a : 0.2f * a;
        }
        float m = a_reg;
#pragma unroll
        for (int off = 32; off; off >>= 1) m = fmaxf(m, __shfl_xor(m, off));
        float ev = valid ? expf(a_reg - m) : 0.0f;
        float ssum = ev;
#pragma unroll
        for (int off = 32; off; off >>= 1) ssum += __shfl_xor(ssum, off);
        const float w_reg = ev / ssum;

        int j = 0;
        for (; j + 8 <= n; j += 8) {
            int   sj[8];
            float wj[8], vj[8];
#pragma unroll
            for (int u = 0; u < 8; u++) {
                sj[u] = __shfl(s_reg, j + u);
                wj[u] = __shfl(w_reg, j + u);
            }
#pragma unroll
            for (int u = 0; u < 8; u++)
                vj[u] = bfu2f(hs[(size_t)sj[u] * (H * 64) + hbase]);
#pragma unroll
            for (int u = 0; u < 8; u++) acc += wj[u] * vj[u];
        }
        for (; j < n; j++) {
            int sj = __shfl(s_reg, j);
            float wj = __shfl(w_reg, j);
            acc += wj * bfu2f(hs[(size_t)sj * (H * 64) + hbase]);
        }
    } else {
        // ---- generic path (rare): 3 passes, 4-wide unrolled gather ----
        float m = -1e30f;
        for (int i = lane; i < n; i += 64) {
            int s = (i < deg) ? csr_src[beg + i] : d;
            float a = es[(size_t)s * H + h] + edh;
            a = (a > 0.0f) ? a : 0.2f * a;
            m = fmaxf(m, a);
        }
#pragma unroll
        for (int off = 32; off; off >>= 1) m = fmaxf(m, __shfl_xor(m, off));
        float ssum = 0.0f;
        for (int i = lane; i < n; i += 64) {
            int s = (i < deg) ? csr_src[beg + i] : d;
            float a = es[(size_t)s * H + h] + edh;
            a = (a > 0.0f) ? a : 0.2f * a;
            ssum += expf(a - m);
        }
#pragma unroll
        for (int off = 32; off; off >>= 1) ssum += __shfl_xor(ssum, off);
        const float inv = 1.0f / ssum;

        for (int base = 0; base < n; base += 64) {
            int i = base + lane;
            int s = d;
            float w = 0.0f;
            if (i < n) {
                s = (i < deg) ? csr_src[beg + i] : d;
                float a = es[(size_t)s * H + h] + edh;
                a = (a > 0.0f) ? a : 0.2f * a;
                w = expf(a - m) * inv;
            }
            int cnt = min(64, n - base);
            int j = 0;
            for (; j + 4 <= cnt; j += 4) {
                int sj[4]; float wj[4], vj[4];
#pragma unroll
                for (int u = 0; u < 4; u++) {
                    sj[u] = __shfl(s, j + u);
                    wj[u] = __shfl(w, j + u);
                }
#pragma unroll
                for (int u = 0; u < 4; u++)
                    vj[u] = bfu2f(hs[(size_t)sj[u] * (H * 64) + hbase]);
#pragma unroll
                for (int u = 0; u < 4; u++) acc += wj[u] * vj[u];
            }
            for (; j < cnt; j++) {
                int sj = __shfl(s, j);
                float wj = __shfl(w, j);
                acc += wj * bfu2f(hs[(size_t)sj * (H * 64) + hbase]);
            }
        }
    }

    if (ELU) {
        float v = acc + bias[h * 64 + lane];
        acc = (v > 0.0f) ? v : expm1f(v);
    }
    out[(size_t)d * (H * 64) + hbase] = acc;
}

// ---------- final: head-mean + bias2, concat with (flat@W+b) and last, 192-dot ----------
__global__ void final_kernel(const float* __restrict__ acc2, const float* __restrict__ bias2,
                             const float* __restrict__ fbuf, const float* __restrict__ flat_b,
                             const float* __restrict__ last, const float* __restrict__ outW,
                             const float* __restrict__ outb, float* __restrict__ out, int N) {
    int n = blockIdx.x * blockDim.x + threadIdx.x;
    if (n >= N) return;
    float s = outb[0];
    const float* a = acc2 + (size_t)n * 256;
    for (int c = 0; c < 64; c++) {
        float h2 = 0.25f * (a[c] + a[64 + c] + a[128 + c] + a[192 + c]) + bias2[c];
        s += h2 * outW[c];
        s += (fbuf[(size_t)n * 64 + c] + flat_b[c]) * outW[64 + c];
        s += last[(size_t)n * 64 + c] * outW[128 + c];
    }
    out[n] = s;
}

// ---------- graph/model dims ----------
#define N1 80000
#define N2 16000
#define N3 4096
#define E1 256000
#define E2 65536

extern "C" void kernel_launch(void* const* d_in, const int* in_sizes, int n_in,
                              void* d_out, int out_size, void* d_ws, size_t ws_size,
                              hipStream_t stream) {
    const float* x    = (const float*)d_in[0];
    const float* flat = (const float*)d_in[1];
    const float* last = (const float*)d_in[2];
    const int*  es1i  = (const int*)d_in[3];
    const int*  ed1i  = (const int*)d_in[4];
    const int*  es2i  = (const int*)d_in[5];
    const int*  ed2i  = (const int*)d_in[6];
    const float* W1s  = (const float*)d_in[7];
    const float* W1d  = (const float*)d_in[8];
    const float* a1s  = (const float*)d_in[9];
    const float* a1d  = (const float*)d_in[10];
    const float* b1   = (const float*)d_in[11];
    const float* W2s  = (const float*)d_in[12];
    const float* W2d  = (const float*)d_in[13];
    const float* a2s  = (const float*)d_in[14];
    const float* a2d  = (const float*)d_in[15];
    const float* b2   = (const float*)d_in[16];
    const float* fW   = (const float*)d_in[17];
    const float* fb   = (const float*)d_in[18];
    const float* oW   = (const float*)d_in[19];
    const float* ob   = (const float*)d_in[20];
    float* out = (float*)d_out;

    float* ws = (float*)d_ws;
    // ---- layout (float-element offsets) ----
    unsigned short* hs1_bf = (unsigned short*)ws;                  // 40,960,000 us = fl[0 .. 20,480,000)
    unsigned short* hd1_bf = (unsigned short*)(ws + 20480000);     //  8,192,000 us -> fl 24,576,000
    float* es1f = ws + 24576000;                                   // 640,000
    float* ed1f = ws + 25216000;                                   // 128,000
    float* acc1 = ws + 25344000;                                   // 8,192,000 -> 33,536,000
    unsigned short* x_hi = (unsigned short*)(ws + 33536000);       // 20,480,000 us
    unsigned short* x_lo = (unsigned short*)(ws + 43776000);       // 20,480,000 us -> fl 54,016,000
    unsigned short* a2_hi = (unsigned short*)(ws + 33536000);      // 8,192,000 us (aliases dead x_hi)
    unsigned short* a2_lo = (unsigned short*)(ws + 37632000);
    unsigned short* f_hi  = (unsigned short*)(ws + 41728000);
    unsigned short* f_lo  = (unsigned short*)(ws + 41990144);
    unsigned short* wbase = (unsigned short*)(ws + 54016000);
    unsigned short* w1s_t3 = wbase;
    unsigned short* w1d_t3 = wbase + 393216;
    unsigned short* w2s_t3 = wbase + 786432;
    unsigned short* w2d_t3 = wbase + 1179648;
    unsigned short* fw_t3  = wbase + 1572864;
    int* ibase   = (int*)(ws + 54816000);
    int* cnt1    = ibase;
    int* start1  = ibase + 16000;
    int* cursor1 = ibase + 32001;
    int* csr1    = ibase + 48001;
    int* cnt2    = ibase + 304001;
    int* start2  = ibase + 308097;
    int* cursor2 = ibase + 312194;
    int* csr2    = ibase + 316290;
    const size_t NEED = ((size_t)54816000 + 381826) * 4;
    if (ws_size < NEED) {
        fprintf(stderr, "kernel_launch: ws_size %zu < needed %zu\n", ws_size, NEED);
        return;
    }
    unsigned short* hs2_bf = (unsigned short*)ws;
    unsigned short* hd2_bf = (unsigned short*)(ws + 2048000);
    float* es2f = ws + 2572288;
    float* ed2f = ws + 2636288;
    float* acc2 = ws + 2652672;
    float* fbuf = ws + 3701248;

    // ---- prep: splits + CSR ----
    split_kernel<<<4096, 256, 0, stream>>>(x, x_hi, x_lo, (size_t)N1 * 256);
    wsplit_kernel<<<(256 * 512 + 255) / 256, 256, 0, stream>>>(W1s, w1s_t3, 256, 512);
    wsplit_kernel<<<(256 * 512 + 255) / 256, 256, 0, stream>>>(W1d, w1d_t3, 256, 512);
    wsplit_kernel<<<(512 * 256 + 255) / 256, 256, 0, stream>>>(W2s, w2s_t3, 512, 256);
    wsplit_kernel<<<(512 * 256 + 255) / 256, 256, 0, stream>>>(W2d, w2d_t3, 512, 256);
    wsplit_kernel<<<(128 * 64 + 255) / 256, 256, 0, stream>>>(fW, fw_t3, 128, 64);
    zeroi_kernel<<<64, 256, 0, stream>>>(cnt1, 16000);
    zeroi_kernel<<<64, 256, 0, stream>>>(cursor1, 16000);
    zeroi_kernel<<<16, 256, 0, stream>>>(cnt2, 4096);
    zeroi_kernel<<<16, 256, 0, stream>>>(cursor2, 4096);
    hist_kernel<<<(E1 + 255) / 256, 256, 0, stream>>>(ed1i, E1, cnt1, N2);
    scan_kernel<<<1, 1024, 0, stream>>>(cnt1, start1, N2);
    fill_kernel<<<(E1 + 255) / 256, 256, 0, stream>>>(es1i, ed1i, E1, start1, cursor1, csr1, N2, N1);
    hist_kernel<<<(E2 + 255) / 256, 256, 0, stream>>>(ed2i, E2, cnt2, N3);
    scan_kernel<<<1, 1024, 0, stream>>>(cnt2, start2, N3);
    fill_kernel<<<(E2 + 255) / 256, 256, 0, stream>>>(es2i, ed2i, E2, start2, cursor2, csr2, N3, N2);

    // ---- layer 1 ----
    gemm_mfma<unsigned short><<<dim3(512 / 64, N1 / 64), 256, 0, stream>>>(
        x_hi, x_lo, w1s_t3, hs1_bf, N1, 512, 256);
    gemm_mfma<unsigned short><<<dim3(512 / 64, N2 / 64), 256, 0, stream>>>(
        x_hi, x_lo, w1d_t3, hd1_bf, N2, 512, 256);
    escore_kernel<<<(N1 * 8 + 255) / 256, 256, 0, stream>>>(hs1_bf, a1s, es1f, N1, 8);
    escore_kernel<<<(N2 * 8 + 255) / 256, 256, 0, stream>>>(hd1_bf, a1d, ed1f, N2, 8);
    gat_agg_kernel<8, true><<<N2, 512, 0, stream>>>(csr1, start1, hs1_bf, es1f, ed1f, b1, acc1, N2);

    // ---- layer 2 ----
    split_kernel<<<4096, 256, 0, stream>>>(acc1, a2_hi, a2_lo, (size_t)N2 * 512);
    gemm_mfma<unsigned short><<<dim3(256 / 64, N2 / 64), 256, 0, stream>>>(
        a2_hi, a2_lo, w2s_t3, hs2_bf, N2, 256, 512);
    gemm_mfma<unsigned short><<<dim3(256 / 64, N3 / 64), 256, 0, stream>>>(
        a2_hi, a2_lo, w2d_t3, hd2_bf, N3, 256, 512);
    escore_kernel<<<(N2 * 4 + 255) / 256, 256, 0, stream>>>(hs2_bf, a2s, es2f, N2, 4);
    escore_kernel<<<(N3 * 4 + 255) / 256, 256, 0, stream>>>(hd2_bf, a2d, ed2f, N3, 4);
    gat_agg_kernel<4, false><<<N3, 256, 0, stream>>>(csr2, start2, hs2_bf, es2f, ed2f, nullptr, acc2, N3);

    // ---- flat MLP + output ----
    split_kernel<<<2048, 256, 0, stream>>>(flat, f_hi, f_lo, (size_t)N3 * 128);
    gemm_mfma<float><<<dim3(64 / 64, N3 / 64), 256, 0, stream>>>(
        f_hi, f_lo, fw_t3, fbuf, N3, 64, 128);
    final_kernel<<<(N3 + 255) / 256, 256, 0, stream>>>(acc2, b2, fbuf, fb, last, oW, ob, out, N3);
}

// Round 7
// 576.146 us; speedup vs baseline: 2.3072x; 1.2323x over previous
//
#include <hip/hip_runtime.h>
#include <hip/hip_bf16.h>
#include <cstdio>

typedef __attribute__((ext_vector_type(8))) short short8;
typedef __attribute__((ext_vector_type(4))) float f32x4;
typedef unsigned short ushort_t;

// ---------- bf16 helpers ----------
__device__ __forceinline__ float bfu2f(unsigned short u) {
    return __uint_as_float(((unsigned)u) << 16);
}
__device__ __forceinline__ unsigned short f2bfu(float f) {   // RNE
    __hip_bfloat16 b = __float2bfloat16(f);
    union { __hip_bfloat16 b; unsigned short u; } cv; cv.b = b;
    return cv.u;
}
__device__ __forceinline__ void store_out(float* p, float v) { *p = v; }
__device__ __forceinline__ void store_out(unsigned short* p, float v) { *p = f2bfu(v); }

// ---------- fills ----------
__global__ void zeroi_kernel(int* __restrict__ p, int n) {
    int i = blockIdx.x * blockDim.x + threadIdx.x;
    int stride = gridDim.x * blockDim.x;
    for (; i < n; i += stride) p[i] = 0;
}

// ---------- CSR build ----------
__global__ void hist_kernel(const int* __restrict__ dst, int E, int* __restrict__ cnt, int Nd) {
    int i = blockIdx.x * blockDim.x + threadIdx.x;
    if (i >= E) return;
    int d = dst[i];
    if ((unsigned)d < (unsigned)Nd) atomicAdd(&cnt[d], 1);
}
__global__ __launch_bounds__(1024)
void scan_kernel(const int* __restrict__ cnt, int* __restrict__ start, int Nd) {
    __shared__ int part[1024];
    int t = threadIdx.x;
    int k = (Nd + 1023) >> 10;
    int lo = t * k, hi = min(lo + k, Nd);
    if (lo > Nd) lo = Nd;
    int s = 0;
    for (int i = lo; i < hi; i++) s += cnt[i];
    part[t] = s;
    __syncthreads();
    for (int off = 1; off < 1024; off <<= 1) {
        int v = (t >= off) ? part[t - off] : 0;
        __syncthreads();
        part[t] += v;
        __syncthreads();
    }
    int run = (t > 0) ? part[t - 1] : 0;
    for (int i = lo; i < hi; i++) { start[i] = run; run += cnt[i]; }
    if (t == 1023) start[Nd] = part[1023];
}
__global__ void fill_kernel(const int* __restrict__ src, const int* __restrict__ dst, int E,
                            const int* __restrict__ start, int* __restrict__ cursor,
                            int* __restrict__ csr_src, int Nd, int Ns) {
    int i = blockIdx.x * blockDim.x + threadIdx.x;
    if (i >= E) return;
    int d = dst[i];
    if ((unsigned)d >= (unsigned)Nd) return;
    int p = atomicAdd(&cursor[d], 1);
    int idx = start[d] + p;
    if (idx >= start[d + 1]) return;
    int s = src[i];
    if ((unsigned)s >= (unsigned)Ns) s = 0;
    csr_src[idx] = s;
}

// ---------- fp32 -> (bf16 hi, bf16 lo), 8 elems/thread, vectorized ----------
__global__ void split8_kernel(const float* __restrict__ X, unsigned short* __restrict__ hi,
                              unsigned short* __restrict__ lo, size_t n8) {
    size_t i = (size_t)blockIdx.x * blockDim.x + threadIdx.x;
    size_t stride = (size_t)gridDim.x * blockDim.x;
    for (; i < n8; i += stride) {
        const float4 v0 = ((const float4*)X)[2 * i];
        const float4 v1 = ((const float4*)X)[2 * i + 1];
        float v[8] = {v0.x, v0.y, v0.z, v0.w, v1.x, v1.y, v1.z, v1.w};
        short8 h, l;
#pragma unroll
        for (int j = 0; j < 8; j++) {
            unsigned short hh = f2bfu(v[j]);
            h[j] = (short)hh;
            l[j] = (short)f2bfu(v[j] - bfu2f(hh));
        }
        ((short8*)hi)[i] = h;
        ((short8*)lo)[i] = l;
    }
}

// ---------- W [K][N] fp32 -> hi[N][K], lo[N][K] bf16 (k-contiguous) ----------
__global__ void wsplit2_kernel(const float* __restrict__ W, unsigned short* __restrict__ hi,
                               unsigned short* __restrict__ lo, int K, int N) {
    int i = blockIdx.x * blockDim.x + threadIdx.x;
    if (i >= K * N) return;
    int k = i / N, n = i - k * N;
    float v = W[i];
    unsigned short h = f2bfu(v);
    hi[(size_t)n * K + k] = h;
    lo[(size_t)n * K + k] = f2bfu(v - bfu2f(h));
}

// ---------- W [K][N] fp32 -> Bt3 [N][3K] bf16 = [hi | lo | hi] (for small flat GEMM) ----------
__global__ void wsplit_kernel(const float* __restrict__ W, unsigned short* __restrict__ Bt3,
                              int K, int N) {
    int i = blockIdx.x * blockDim.x + threadIdx.x;
    if (i >= K * N) return;
    int k = i / N, n = i - k * N;
    float v = W[(size_t)k * N + n];
    unsigned short h = f2bfu(v);
    unsigned short l = f2bfu(v - bfu2f(h));
    size_t base = (size_t)n * (3 * K);
    Bt3[base + k] = h;
    Bt3[base + K + k] = l;
    Bt3[base + 2 * K + k] = h;
}

// ---------- MAIN MFMA GEMM: C[M,N] = A@B, bf16x3 split, 64x256 tile ----------
// A: (Ahi, Alo) [M][K]; B: (Bhi, Blo) [N][K] k-contiguous. Requires M%64==0, N%256==0, K%32==0.
// 256 threads = 4 waves; wave w owns rows[0..64) x cols[w*64..w*64+64).
__global__ __launch_bounds__(256, 3)
void gemm_mfma2(const unsigned short* __restrict__ Ahi, const unsigned short* __restrict__ Alo,
                const unsigned short* __restrict__ Bhi, const unsigned short* __restrict__ Blo,
                unsigned short* __restrict__ C, int M, int N, int K) {
    __shared__ unsigned short As[2][64][40];    // [hi/lo][row][k], pad 32->40 (2-way free)
    __shared__ unsigned short Bs[2][256][40];
    const int tid = threadIdx.x;
    const int wave = tid >> 6, lane = tid & 63;
    const int quad = lane >> 4, l15 = lane & 15;
    const int m0 = blockIdx.y * 64, n0 = blockIdx.x * 256;
    const int arow = tid >> 2, acol = (tid & 3) * 8;
    f32x4 acc[4][4] = {};
    for (int k0 = 0; k0 < K; k0 += 32) {
        // stage A: 64x32 hi + lo (one short8 per thread each)
        *(short8*)&As[0][arow][acol] = *(const short8*)&Ahi[(size_t)(m0 + arow) * K + k0 + acol];
        *(short8*)&As[1][arow][acol] = *(const short8*)&Alo[(size_t)(m0 + arow) * K + k0 + acol];
        // stage B: 256x32 hi + lo (four short8 per thread each)
#pragma unroll
        for (int i = 0; i < 4; i++) {
            int brow = arow + 64 * i;
            *(short8*)&Bs[0][brow][acol] = *(const short8*)&Bhi[(size_t)(n0 + brow) * K + k0 + acol];
            *(short8*)&Bs[1][brow][acol] = *(const short8*)&Blo[(size_t)(n0 + brow) * K + k0 + acol];
        }
        __syncthreads();
        short8 ah[4], al[4];
#pragma unroll
        for (int t = 0; t < 4; t++) {
            ah[t] = *(const short8*)&As[0][t * 16 + l15][quad * 8];
            al[t] = *(const short8*)&As[1][t * 16 + l15][quad * 8];
        }
#pragma unroll
        for (int nt = 0; nt < 4; nt++) {
            short8 bh = *(const short8*)&Bs[0][wave * 64 + nt * 16 + l15][quad * 8];
            short8 bl = *(const short8*)&Bs[1][wave * 64 + nt * 16 + l15][quad * 8];
#pragma unroll
            for (int mt = 0; mt < 4; mt++) {
                acc[mt][nt] = __builtin_amdgcn_mfma_f32_16x16x32_bf16(ah[mt], bh, acc[mt][nt], 0, 0, 0);
                acc[mt][nt] = __builtin_amdgcn_mfma_f32_16x16x32_bf16(ah[mt], bl, acc[mt][nt], 0, 0, 0);
                acc[mt][nt] = __builtin_amdgcn_mfma_f32_16x16x32_bf16(al[mt], bh, acc[mt][nt], 0, 0, 0);
            }
        }
        __syncthreads();
    }
#pragma unroll
    for (int mt = 0; mt < 4; mt++)
#pragma unroll
        for (int nt = 0; nt < 4; nt++)
#pragma unroll
            for (int r = 0; r < 4; r++) {
                int row = m0 + mt * 16 + quad * 4 + r;
                int col = n0 + wave * 64 + nt * 16 + l15;
                C[(size_t)row * N + col] = f2bfu(acc[mt][nt][r]);
            }
}

// ---------- small MFMA GEMM (64x64 tile, Bt3 layout) — used for flat (N=64) only ----------
template <typename OutT>
__global__ __launch_bounds__(256)
void gemm_mfma(const unsigned short* __restrict__ Ahi, const unsigned short* __restrict__ Alo,
               const unsigned short* __restrict__ Bt3, OutT* __restrict__ C,
               int M, int N, int K) {
    const int KK = 3 * K;
    __shared__ unsigned short As[64][72];
    __shared__ unsigned short Bs[64][72];
    const int tid = threadIdx.x;
    const int wave = tid >> 6, lane = tid & 63;
    const int wr = wave >> 1, wc = wave & 1;
    const int quad = lane >> 4, l15 = lane & 15;
    const int m0 = blockIdx.y * 64, n0 = blockIdx.x * 64;
    f32x4 acc[2][2] = {};
    for (int k0 = 0; k0 < KK; k0 += 64) {
        const int seg = k0 / K;
        const int ks = k0 - seg * K;
        const unsigned short* Asrc = (seg < 2) ? Ahi : Alo;
#pragma unroll
        for (int i = 0; i < 2; i++) {
            int idx = tid + i * 256;
            int r = idx >> 3, cv = (idx & 7) * 8;
            *(short8*)&As[r][cv] = *(const short8*)&Asrc[(size_t)(m0 + r) * K + ks + cv];
            *(short8*)&Bs[r][cv] = *(const short8*)&Bt3[(size_t)(n0 + r) * KK + k0 + cv];
        }
        __syncthreads();
#pragma unroll
        for (int kk = 0; kk < 64; kk += 32) {
            short8 a[2], b[2];
#pragma unroll
            for (int t = 0; t < 2; t++) {
                a[t] = *(const short8*)&As[wr * 32 + t * 16 + l15][kk + quad * 8];
                b[t] = *(const short8*)&Bs[wc * 32 + t * 16 + l15][kk + quad * 8];
            }
#pragma unroll
            for (int mt = 0; mt < 2; mt++)
#pragma unroll
                for (int nt = 0; nt < 2; nt++)
                    acc[mt][nt] = __builtin_amdgcn_mfma_f32_16x16x32_bf16(
                        a[mt], b[nt], acc[mt][nt], 0, 0, 0);
        }
        __syncthreads();
    }
#pragma unroll
    for (int mt = 0; mt < 2; mt++)
#pragma unroll
        for (int nt = 0; nt < 2; nt++)
#pragma unroll
            for (int r = 0; r < 4; r++) {
                int row = m0 + wr * 32 + mt * 16 + quad * 4 + r;
                int col = n0 + wc * 32 + nt * 16 + l15;
                store_out(&C[(size_t)row * N + col], acc[mt][nt][r]);
            }
}

// ---------- e[n,h] = sum_c h_bf[n,h,c] * att[h,c], C=64, short8 loads ----------
__global__ void escore_kernel(const unsigned short* __restrict__ h, const float* __restrict__ att,
                              float* __restrict__ e, int N, int H) {
    int i = blockIdx.x * blockDim.x + threadIdx.x;
    if (i >= N * H) return;
    int n = i / H, hh = i - n * H;
    const short8* hp = (const short8*)(h + (size_t)n * H * 64 + hh * 64);
    const float* ap = att + hh * 64;
    float s = 0.0f;
#pragma unroll
    for (int c8 = 0; c8 < 8; c8++) {
        short8 v = hp[c8];
#pragma unroll
        for (int j = 0; j < 8; j++)
            s += bfu2f((unsigned short)v[j]) * ap[c8 * 8 + j];
    }
    e[i] = s;
}

// ---------- fused GAT aggregate: one wave per (dst, head); register fast-path + ILP-8 gather ----------
template <int H, bool ELU>
__global__ void gat_agg_kernel(const int* __restrict__ csr_src, const int* __restrict__ row_start,
                               const unsigned short* __restrict__ hs,  // [Ns,H,64] bf16
                               const float* __restrict__ es,           // [Ns,H]
                               const float* __restrict__ ed,           // [Nd,H]
                               const float* __restrict__ bias,         // [H*64] or null
                               float* __restrict__ out,                // [Nd,H,64] fp32
                               int Nd) {
    const int d = blockIdx.x;
    const int h = threadIdx.x >> 6;
    const int lane = threadIdx.x & 63;
    const int beg = row_start[d];
    const int deg = row_start[d + 1] - beg;
    const int n = deg + 1;                 // + self loop
    const float edh = ed[(size_t)d * H + h];
    const size_t hbase = (size_t)h * 64 + lane;
    float acc = 0.0f;

    if (n <= 64) {
        const bool valid = lane < n;
        int s_reg = d;
        float a_reg = -1e30f;
        if (valid) {
            s_reg = (lane < deg) ? csr_src[beg + lane] : d;
            float a = es[(size_t)s_reg * H + h] + edh;
            a_reg = (a > 0.0f) ? a : 0.2f * a;
        }
        float m = a_reg;
#pragma unroll
        for (int off = 32; off; off >>= 1) m = fmaxf(m, __shfl_xor(m, off));
        float ev = valid ? expf(a_reg - m) : 0.0f;
        float ssum = ev;
#pragma unroll
        for (int off = 32; off; off >>= 1) ssum += __shfl_xor(ssum, off);
        const float w_reg = ev / ssum;

        int j = 0;
        for (; j + 8 <= n; j += 8) {
            int   sj[8];
            float wj[8], vj[8];
#pragma unroll
            for (int u = 0; u < 8; u++) {
                sj[u] = __shfl(s_reg, j + u);
                wj[u] = __shfl(w_reg, j + u);
            }
#pragma unroll
            for (int u = 0; u < 8; u++)
                vj[u] = bfu2f(hs[(size_t)sj[u] * (H * 64) + hbase]);
#pragma unroll
            for (int u = 0; u < 8; u++) acc += wj[u] * vj[u];
        }
        for (; j < n; j++) {
            int sj = __shfl(s_reg, j);
            float wj = __shfl(w_reg, j);
            acc += wj * bfu2f(hs[(size_t)sj * (H * 64) + hbase]);
        }
    } else {
        float m = -1e30f;
        for (int i = lane; i < n; i += 64) {
            int s = (i < deg) ? csr_src[beg + i] : d;
            float a = es[(size_t)s * H + h] + edh;
            a = (a > 0.0f) ? a : 0.2f * a;
            m = fmaxf(m, a);
        }
#pragma unroll
        for (int off = 32; off; off >>= 1) m = fmaxf(m, __shfl_xor(m, off));
        float ssum = 0.0f;
        for (int i = lane; i < n; i += 64) {
            int s = (i < deg) ? csr_src[beg + i] : d;
            float a = es[(size_t)s * H + h] + edh;
            a = (a > 0.0f) ? a : 0.2f * a;
            ssum += expf(a - m);
        }
#pragma unroll
        for (int off = 32; off; off >>= 1) ssum += __shfl_xor(ssum, off);
        const float inv = 1.0f / ssum;

        for (int base = 0; base < n; base += 64) {
            int i = base + lane;
            int s = d;
            float w = 0.0f;
            if (i < n) {
                s = (i < deg) ? csr_src[beg + i] : d;
                float a = es[(size_t)s * H + h] + edh;
                a = (a > 0.0f) ? a : 0.2f * a;
                w = expf(a - m) * inv;
            }
            int cnt = min(64, n - base);
            int j = 0;
            for (; j + 4 <= cnt; j += 4) {
                int sj[4]; float wj[4], vj[4];
#pragma unroll
                for (int u = 0; u < 4; u++) {
                    sj[u] = __shfl(s, j + u);
                    wj[u] = __shfl(w, j + u);
                }
#pragma unroll
                for (int u = 0; u < 4; u++)
                    vj[u] = bfu2f(hs[(size_t)sj[u] * (H * 64) + hbase]);
#pragma unroll
                for (int u = 0; u < 4; u++) acc += wj[u] * vj[u];
            }
            for (; j < cnt; j++) {
                int sj = __shfl(s, j);
                float wj = __shfl(w, j);
                acc += wj * bfu2f(hs[(size_t)sj * (H * 64) + hbase]);
            }
        }
    }

    if (ELU) {
        float v = acc + bias[h * 64 + lane];
        acc = (v > 0.0f) ? v : expm1f(v);
    }
    out[(size_t)d * (H * 64) + hbase] = acc;
}

// ---------- final: head-mean + bias2, concat with (flat@W+b) and last, 192-dot ----------
__global__ void final_kernel(const float* __restrict__ acc2, const float* __restrict__ bias2,
                             const float* __restrict__ fbuf, const float* __restrict__ flat_b,
                             const float* __restrict__ last, const float* __restrict__ outW,
                             const float* __restrict__ outb, float* __restrict__ out, int N) {
    int n = blockIdx.x * blockDim.x + threadIdx.x;
    if (n >= N) return;
    float s = outb[0];
    const float* a = acc2 + (size_t)n * 256;
    for (int c = 0; c < 64; c++) {
        float h2 = 0.25f * (a[c] + a[64 + c] + a[128 + c] + a[192 + c]) + bias2[c];
        s += h2 * outW[c];
        s += (fbuf[(size_t)n * 64 + c] + flat_b[c]) * outW[64 + c];
        s += last[(size_t)n * 64 + c] * outW[128 + c];
    }
    out[n] = s;
}

// ---------- graph/model dims ----------
#define N1 80000
#define N2 16000
#define N3 4096
#define E1 256000
#define E2 65536

extern "C" void kernel_launch(void* const* d_in, const int* in_sizes, int n_in,
                              void* d_out, int out_size, void* d_ws, size_t ws_size,
                              hipStream_t stream) {
    const float* x    = (const float*)d_in[0];
    const float* flat = (const float*)d_in[1];
    const float* last = (const float*)d_in[2];
    const int*  es1i  = (const int*)d_in[3];
    const int*  ed1i  = (const int*)d_in[4];
    const int*  es2i  = (const int*)d_in[5];
    const int*  ed2i  = (const int*)d_in[6];
    const float* W1s  = (const float*)d_in[7];
    const float* W1d  = (const float*)d_in[8];
    const float* a1s  = (const float*)d_in[9];
    const float* a1d  = (const float*)d_in[10];
    const float* b1   = (const float*)d_in[11];
    const float* W2s  = (const float*)d_in[12];
    const float* W2d  = (const float*)d_in[13];
    const float* a2s  = (const float*)d_in[14];
    const float* a2d  = (const float*)d_in[15];
    const float* b2   = (const float*)d_in[16];
    const float* fW   = (const float*)d_in[17];
    const float* fb   = (const float*)d_in[18];
    const float* oW   = (const float*)d_in[19];
    const float* ob   = (const float*)d_in[20];
    float* out = (float*)d_out;

    float* ws = (float*)d_ws;
    // ---- layout (float-element offsets) ----
    unsigned short* hs1_bf = (unsigned short*)ws;                  // 40,960,000 us = fl[0 .. 20,480,000)
    unsigned short* hd1_bf = (unsigned short*)(ws + 20480000);     //  8,192,000 us -> fl 24,576,000
    float* es1f = ws + 24576000;                                   // 640,000
    float* ed1f = ws + 25216000;                                   // 128,000
    float* acc1 = ws + 25344000;                                   // 8,192,000 -> 33,536,000
    unsigned short* x_hi = (unsigned short*)(ws + 33536000);       // 20,480,000 us
    unsigned short* x_lo = (unsigned short*)(ws + 43776000);       // 20,480,000 us -> fl 54,016,000
    unsigned short* a2h  = (unsigned short*)(ws + 33536000);       // aliases dead x region
    unsigned short* a2l  = (unsigned short*)(ws + 37632000);
    unsigned short* f_hi = (unsigned short*)(ws + 41728000);
    unsigned short* f_lo = (unsigned short*)(ws + 41990144);
    // weights: region [54,016,000 .. 54,816,000) = 1.6M ushorts capacity
    unsigned short* wb = (unsigned short*)(ws + 54016000);
    unsigned short* w1s_hi = wb;                // 512*256 = 131,072 each
    unsigned short* w1s_lo = wb + 131072;
    unsigned short* w1d_hi = wb + 262144;
    unsigned short* w1d_lo = wb + 393216;
    unsigned short* w2s_hi = wb + 524288;       // 256*512 = 131,072 each
    unsigned short* w2s_lo = wb + 655360;
    unsigned short* w2d_hi = wb + 786432;
    unsigned short* w2d_lo = wb + 917504;
    unsigned short* fw_t3  = wb + 1048576;      // 64*384 = 24,576 -> 1,073,152 total
    // ints
    int* ibase   = (int*)(ws + 54816000);
    int* cnt1    = ibase;                       // 16,000
    int* cursor1 = ibase + 16000;               // 16,000
    int* cnt2    = ibase + 32000;               //  4,096
    int* cursor2 = ibase + 36096;               //  4,096  (zero block: 40,192 ints)
    int* start1  = ibase + 40192;               // 16,001
    int* start2  = ibase + 56193;               //  4,097
    int* csr1    = ibase + 60290;               // 256,000
    int* csr2    = ibase + 316290;              // 65,536 -> 381,826 ints
    const size_t NEED = ((size_t)54816000 + 381826) * 4;
    if (ws_size < NEED) {
        fprintf(stderr, "kernel_launch: ws_size %zu < needed %zu\n", ws_size, NEED);
        return;
    }
    unsigned short* hs2_bf = (unsigned short*)ws;
    unsigned short* hd2_bf = (unsigned short*)(ws + 2048000);
    float* es2f = ws + 2572288;
    float* ed2f = ws + 2636288;
    float* acc2 = ws + 2652672;
    float* fbuf = ws + 3701248;

    // ---- prep: splits + CSR ----
    split8_kernel<<<2048, 256, 0, stream>>>(x, x_hi, x_lo, (size_t)N1 * 256 / 8);
    wsplit2_kernel<<<(256 * 512 + 255) / 256, 256, 0, stream>>>(W1s, w1s_hi, w1s_lo, 256, 512);
    wsplit2_kernel<<<(256 * 512 + 255) / 256, 256, 0, stream>>>(W1d, w1d_hi, w1d_lo, 256, 512);
    wsplit2_kernel<<<(512 * 256 + 255) / 256, 256, 0, stream>>>(W2s, w2s_hi, w2s_lo, 512, 256);
    wsplit2_kernel<<<(512 * 256 + 255) / 256, 256, 0, stream>>>(W2d, w2d_hi, w2d_lo, 512, 256);
    wsplit_kernel<<<(128 * 64 + 255) / 256, 256, 0, stream>>>(fW, fw_t3, 128, 64);
    zeroi_kernel<<<160, 256, 0, stream>>>(ibase, 40192);
    hist_kernel<<<(E1 + 255) / 256, 256, 0, stream>>>(ed1i, E1, cnt1, N2);
    scan_kernel<<<1, 1024, 0, stream>>>(cnt1, start1, N2);
    fill_kernel<<<(E1 + 255) / 256, 256, 0, stream>>>(es1i, ed1i, E1, start1, cursor1, csr1, N2, N1);
    hist_kernel<<<(E2 + 255) / 256, 256, 0, stream>>>(ed2i, E2, cnt2, N3);
    scan_kernel<<<1, 1024, 0, stream>>>(cnt2, start2, N3);
    fill_kernel<<<(E2 + 255) / 256, 256, 0, stream>>>(es2i, ed2i, E2, start2, cursor2, csr2, N3, N2);

    // ---- layer 1 ----
    gemm_mfma2<<<dim3(2, N1 / 64), 256, 0, stream>>>(x_hi, x_lo, w1s_hi, w1s_lo, hs1_bf, N1, 512, 256);
    gemm_mfma2<<<dim3(2, N2 / 64), 256, 0, stream>>>(x_hi, x_lo, w1d_hi, w1d_lo, hd1_bf, N2, 512, 256);
    escore_kernel<<<(N1 * 8 + 255) / 256, 256, 0, stream>>>(hs1_bf, a1s, es1f, N1, 8);
    escore_kernel<<<(N2 * 8 + 255) / 256, 256, 0, stream>>>(hd1_bf, a1d, ed1f, N2, 8);
    gat_agg_kernel<8, true><<<N2, 512, 0, stream>>>(csr1, start1, hs1_bf, es1f, ed1f, b1, acc1, N2);

    // ---- layer 2 ----
    split8_kernel<<<2048, 256, 0, stream>>>(acc1, a2h, a2l, (size_t)N2 * 512 / 8);
    gemm_mfma2<<<dim3(1, N2 / 64), 256, 0, stream>>>(a2h, a2l, w2s_hi, w2s_lo, hs2_bf, N2, 256, 512);
    gemm_mfma2<<<dim3(1, N3 / 64), 256, 0, stream>>>(a2h, a2l, w2d_hi, w2d_lo, hd2_bf, N3, 256, 512);
    escore_kernel<<<(N2 * 4 + 255) / 256, 256, 0, stream>>>(hs2_bf, a2s, es2f, N2, 4);
    escore_kernel<<<(N3 * 4 + 255) / 256, 256, 0, stream>>>(hd2_bf, a2d, ed2f, N3, 4);
    gat_agg_kernel<4, false><<<N3, 256, 0, stream>>>(csr2, start2, hs2_bf, es2f, ed2f, nullptr, acc2, N3);

    // ---- flat MLP + output ----
    split8_kernel<<<512, 256, 0, stream>>>(flat, f_hi, f_lo, (size_t)N3 * 128 / 8);
    gemm_mfma<float><<<dim3(1, N3 / 64), 256, 0, stream>>>(f_hi, f_lo, fw_t3, fbuf, N3, 64, 128);
    final_kernel<<<(N3 + 255) / 256, 256, 0, stream>>>(acc2, b2, fbuf, fb, last, oW, ob, out, N3);
}

// Round 8
// 522.077 us; speedup vs baseline: 2.5461x; 1.1036x over previous
//
#include <hip/hip_runtime.h>
#include <hip/hip_bf16.h>
#include <cstdio>

typedef __attribute__((ext_vector_type(8))) short short8;
typedef __attribute__((ext_vector_type(4))) short short4v;
typedef __attribute__((ext_vector_type(4))) float f32x4;

template <int H> struct VecT;
template <> struct VecT<8> { using T = short8; };
template <> struct VecT<4> { using T = short4v; };

// ---------- bf16 helpers ----------
__device__ __forceinline__ float bfu2f(unsigned short u) {
    return __uint_as_float(((unsigned)u) << 16);
}
__device__ __forceinline__ unsigned short f2bfu(float f) {   // RNE
    __hip_bfloat16 b = __float2bfloat16(f);
    union { __hip_bfloat16 b; unsigned short u; } cv; cv.b = b;
    return cv.u;
}
__device__ __forceinline__ void store_out(float* p, float v) { *p = v; }
__device__ __forceinline__ void store_out(unsigned short* p, float v) { *p = f2bfu(v); }

// ---------- fills ----------
__global__ void zeroi_kernel(int* __restrict__ p, int n) {
    int i = blockIdx.x * blockDim.x + threadIdx.x;
    int stride = gridDim.x * blockDim.x;
    for (; i < n; i += stride) p[i] = 0;
}

// ---------- CSR build ----------
__global__ void hist_kernel(const int* __restrict__ dst, int E, int* __restrict__ cnt, int Nd) {
    int i = blockIdx.x * blockDim.x + threadIdx.x;
    if (i >= E) return;
    int d = dst[i];
    if ((unsigned)d < (unsigned)Nd) atomicAdd(&cnt[d], 1);
}
__global__ __launch_bounds__(1024)
void scan_kernel(const int* __restrict__ cnt, int* __restrict__ start, int Nd) {
    __shared__ int part[1024];
    int t = threadIdx.x;
    int k = (Nd + 1023) >> 10;
    int lo = t * k, hi = min(lo + k, Nd);
    if (lo > Nd) lo = Nd;
    int s = 0;
    for (int i = lo; i < hi; i++) s += cnt[i];
    part[t] = s;
    __syncthreads();
    for (int off = 1; off < 1024; off <<= 1) {
        int v = (t >= off) ? part[t - off] : 0;
        __syncthreads();
        part[t] += v;
        __syncthreads();
    }
    int run = (t > 0) ? part[t - 1] : 0;
    for (int i = lo; i < hi; i++) { start[i] = run; run += cnt[i]; }
    if (t == 1023) start[Nd] = part[1023];
}
__global__ void fill_kernel(const int* __restrict__ src, const int* __restrict__ dst, int E,
                            const int* __restrict__ start, int* __restrict__ cursor,
                            int* __restrict__ csr_src, int Nd, int Ns) {
    int i = blockIdx.x * blockDim.x + threadIdx.x;
    if (i >= E) return;
    int d = dst[i];
    if ((unsigned)d >= (unsigned)Nd) return;
    int p = atomicAdd(&cursor[d], 1);
    int idx = start[d] + p;
    if (idx >= start[d + 1]) return;
    int s = src[i];
    if ((unsigned)s >= (unsigned)Ns) s = 0;
    csr_src[idx] = s;
}

// ---------- fp32 -> (bf16 hi, bf16 lo), 8 elems/thread ----------
__global__ void split8_kernel(const float* __restrict__ X, unsigned short* __restrict__ hi,
                              unsigned short* __restrict__ lo, size_t n8) {
    size_t i = (size_t)blockIdx.x * blockDim.x + threadIdx.x;
    size_t stride = (size_t)gridDim.x * blockDim.x;
    for (; i < n8; i += stride) {
        const float4 v0 = ((const float4*)X)[2 * i];
        const float4 v1 = ((const float4*)X)[2 * i + 1];
        float v[8] = {v0.x, v0.y, v0.z, v0.w, v1.x, v1.y, v1.z, v1.w};
        short8 h, l;
#pragma unroll
        for (int j = 0; j < 8; j++) {
            unsigned short hh = f2bfu(v[j]);
            h[j] = (short)hh;
            l[j] = (short)f2bfu(v[j] - bfu2f(hh));
        }
        ((short8*)hi)[i] = h;
        ((short8*)lo)[i] = l;
    }
}

// ---------- W [K][N] fp32 -> hi[N][K], lo[N][K] bf16 ----------
__global__ void wsplit2_kernel(const float* __restrict__ W, unsigned short* __restrict__ hi,
                               unsigned short* __restrict__ lo, int K, int N) {
    int i = blockIdx.x * blockDim.x + threadIdx.x;
    if (i >= K * N) return;
    int k = i / N, n = i - k * N;
    float v = W[i];
    unsigned short h = f2bfu(v);
    hi[(size_t)n * K + k] = h;
    lo[(size_t)n * K + k] = f2bfu(v - bfu2f(h));
}

// ---------- W [K][N] fp32 -> Bt3 [N][3K] = [hi|lo|hi] (flat GEMM) ----------
__global__ void wsplit_kernel(const float* __restrict__ W, unsigned short* __restrict__ Bt3,
                              int K, int N) {
    int i = blockIdx.x * blockDim.x + threadIdx.x;
    if (i >= K * N) return;
    int k = i / N, n = i - k * N;
    float v = W[(size_t)k * N + n];
    unsigned short h = f2bfu(v);
    unsigned short l = f2bfu(v - bfu2f(h));
    size_t base = (size_t)n * (3 * K);
    Bt3[base + k] = h;
    Bt3[base + K + k] = l;
    Bt3[base + 2 * K + k] = h;
}

// ---------- MAIN MFMA GEMM, 64x256 tile, optional fused escore epilogue ----------
// es[row, head] = sum_c C_f32[row, head*64+c] * att[head*64+c]   (head = col/64)
__global__ __launch_bounds__(256, 3)
void gemm_mfma2(const unsigned short* __restrict__ Ahi, const unsigned short* __restrict__ Alo,
                const unsigned short* __restrict__ Bhi, const unsigned short* __restrict__ Blo,
                unsigned short* __restrict__ C, int M, int N, int K,
                const float* __restrict__ att, float* __restrict__ es_out, int H) {
    __shared__ unsigned short As[2][64][40];
    __shared__ unsigned short Bs[2][256][40];
    const int tid = threadIdx.x;
    const int wave = tid >> 6, lane = tid & 63;
    const int quad = lane >> 4, l15 = lane & 15;
    const int m0 = blockIdx.y * 64, n0 = blockIdx.x * 256;
    const int arow = tid >> 2, acol = (tid & 3) * 8;
    f32x4 acc[4][4] = {};
    for (int k0 = 0; k0 < K; k0 += 32) {
        *(short8*)&As[0][arow][acol] = *(const short8*)&Ahi[(size_t)(m0 + arow) * K + k0 + acol];
        *(short8*)&As[1][arow][acol] = *(const short8*)&Alo[(size_t)(m0 + arow) * K + k0 + acol];
#pragma unroll
        for (int i = 0; i < 4; i++) {
            int brow = arow + 64 * i;
            *(short8*)&Bs[0][brow][acol] = *(const short8*)&Bhi[(size_t)(n0 + brow) * K + k0 + acol];
            *(short8*)&Bs[1][brow][acol] = *(const short8*)&Blo[(size_t)(n0 + brow) * K + k0 + acol];
        }
        __syncthreads();
        short8 ah[4], al[4];
#pragma unroll
        for (int t = 0; t < 4; t++) {
            ah[t] = *(const short8*)&As[0][t * 16 + l15][quad * 8];
            al[t] = *(const short8*)&As[1][t * 16 + l15][quad * 8];
        }
#pragma unroll
        for (int nt = 0; nt < 4; nt++) {
            short8 bh = *(const short8*)&Bs[0][wave * 64 + nt * 16 + l15][quad * 8];
            short8 bl = *(const short8*)&Bs[1][wave * 64 + nt * 16 + l15][quad * 8];
#pragma unroll
            for (int mt = 0; mt < 4; mt++) {
                acc[mt][nt] = __builtin_amdgcn_mfma_f32_16x16x32_bf16(ah[mt], bh, acc[mt][nt], 0, 0, 0);
                acc[mt][nt] = __builtin_amdgcn_mfma_f32_16x16x32_bf16(ah[mt], bl, acc[mt][nt], 0, 0, 0);
                acc[mt][nt] = __builtin_amdgcn_mfma_f32_16x16x32_bf16(al[mt], bh, acc[mt][nt], 0, 0, 0);
            }
        }
        __syncthreads();
    }
#pragma unroll
    for (int mt = 0; mt < 4; mt++)
#pragma unroll
        for (int nt = 0; nt < 4; nt++)
#pragma unroll
            for (int r = 0; r < 4; r++) {
                int row = m0 + mt * 16 + quad * 4 + r;
                int col = n0 + wave * 64 + nt * 16 + l15;
                C[(size_t)row * N + col] = f2bfu(acc[mt][nt][r]);
            }
    if (att != nullptr) {
        const int head = (n0 >> 6) + wave;
        float av[4];
#pragma unroll
        for (int nt = 0; nt < 4; nt++) av[nt] = att[head * 64 + nt * 16 + l15];
#pragma unroll
        for (int mt = 0; mt < 4; mt++)
#pragma unroll
            for (int r = 0; r < 4; r++) {
                float p = acc[mt][0][r] * av[0] + acc[mt][1][r] * av[1]
                        + acc[mt][2][r] * av[2] + acc[mt][3][r] * av[3];
#pragma unroll
                for (int off = 1; off < 16; off <<= 1) p += __shfl_xor(p, off);
                if (l15 == 0)
                    es_out[(size_t)(m0 + mt * 16 + quad * 4 + r) * H + head] = p;
            }
    }
}

// ---------- small MFMA GEMM (64x64 tile, Bt3 layout) — flat GEMM only ----------
template <typename OutT>
__global__ __launch_bounds__(256)
void gemm_mfma(const unsigned short* __restrict__ Ahi, const unsigned short* __restrict__ Alo,
               const unsigned short* __restrict__ Bt3, OutT* __restrict__ C,
               int M, int N, int K) {
    const int KK = 3 * K;
    __shared__ unsigned short As[64][72];
    __shared__ unsigned short Bs[64][72];
    const int tid = threadIdx.x;
    const int wave = tid >> 6, lane = tid & 63;
    const int wr = wave >> 1, wc = wave & 1;
    const int quad = lane >> 4, l15 = lane & 15;
    const int m0 = blockIdx.y * 64, n0 = blockIdx.x * 64;
    f32x4 acc[2][2] = {};
    for (int k0 = 0; k0 < KK; k0 += 64) {
        const int seg = k0 / K;
        const int ks = k0 - seg * K;
        const unsigned short* Asrc = (seg < 2) ? Ahi : Alo;
#pragma unroll
        for (int i = 0; i < 2; i++) {
            int idx = tid + i * 256;
            int r = idx >> 3, cv = (idx & 7) * 8;
            *(short8*)&As[r][cv] = *(const short8*)&Asrc[(size_t)(m0 + r) * K + ks + cv];
            *(short8*)&Bs[r][cv] = *(const short8*)&Bt3[(size_t)(n0 + r) * KK + k0 + cv];
        }
        __syncthreads();
#pragma unroll
        for (int kk = 0; kk < 64; kk += 32) {
            short8 a[2], b[2];
#pragma unroll
            for (int t = 0; t < 2; t++) {
                a[t] = *(const short8*)&As[wr * 32 + t * 16 + l15][kk + quad * 8];
                b[t] = *(const short8*)&Bs[wc * 32 + t * 16 + l15][kk + quad * 8];
            }
#pragma unroll
            for (int mt = 0; mt < 2; mt++)
#pragma unroll
                for (int nt = 0; nt < 2; nt++)
                    acc[mt][nt] = __builtin_amdgcn_mfma_f32_16x16x32_bf16(
                        a[mt], b[nt], acc[mt][nt], 0, 0, 0);
        }
        __syncthreads();
    }
#pragma unroll
    for (int mt = 0; mt < 2; mt++)
#pragma unroll
        for (int nt = 0; nt < 2; nt++)
#pragma unroll
            for (int r = 0; r < 4; r++) {
                int row = m0 + wr * 32 + mt * 16 + quad * 4 + r;
                int col = n0 + wc * 32 + nt * 16 + l15;
                store_out(&C[(size_t)row * N + col], acc[mt][nt][r]);
            }
}

// ---------- GAT aggregate v2: one WAVE per dst node, all heads; coalesced 1KB row gathers ----------
// block = 256 (4 nodes), grid = Nd/4. Phase A: lane=(e_sub,h). Phase B: lane covers H channels.
template <int H, bool ELU>
__global__ __launch_bounds__(256)
void gat_agg2(const int* __restrict__ csr, const int* __restrict__ rs,
              const unsigned short* __restrict__ hs,  // [Ns, H*64] bf16
              const float* __restrict__ es,           // [Ns, H]
              const float* __restrict__ ed,           // [Nd, H]
              const float* __restrict__ bias,         // [H*64] or null
              float* __restrict__ out,                // [Nd, H*64] fp32
              int Nd) {
    constexpr int LH = (H == 8) ? 3 : 2;
    constexpr int EPC = 64 >> LH;          // edges per chunk in phase A
    const int lane = threadIdx.x & 63;
    const int d = blockIdx.x * (blockDim.x >> 6) + (threadIdx.x >> 6);
    if (d >= Nd) return;
    const int beg = rs[d];
    const int deg = rs[d + 1] - beg;
    const int n = deg + 1;                 // + self loop
    // ---- phase A: per-head max & denom ----
    const int h = lane & (H - 1);
    const int e0 = lane >> LH;
    const float edh = ed[(size_t)d * H + h];
    float mx = -1e30f;
    for (int j0 = 0; j0 < n; j0 += EPC) {
        int j = j0 + e0;
        if (j < n) {
            int s = (j < deg) ? csr[beg + j] : d;
            float a = es[(size_t)s * H + h] + edh;
            a = (a > 0.0f) ? a : 0.2f * a;
            mx = fmaxf(mx, a);
        }
    }
#pragma unroll
    for (int off = H; off < 64; off <<= 1) mx = fmaxf(mx, __shfl_xor(mx, off));
    float den = 0.0f;
    for (int j0 = 0; j0 < n; j0 += EPC) {
        int j = j0 + e0;
        if (j < n) {
            int s = (j < deg) ? csr[beg + j] : d;
            float a = es[(size_t)s * H + h] + edh;
            a = (a > 0.0f) ? a : 0.2f * a;
            den += expf(a - mx);
        }
    }
#pragma unroll
    for (int off = H; off < 64; off <<= 1) den += __shfl_xor(den, off);
    const float inv = 1.0f / den;
    // ---- phase B: lane owns H channels (lane*H .. lane*H+H) ----
    const int hB = lane >> (6 - LH);
    const float mB = __shfl(mx, hB);
    const float invB = __shfl(inv, hB);
    const float edhB = __shfl(edh, hB);
    using V = typename VecT<H>::T;
    float acc[H] = {};
    const size_t rowoff = (size_t)lane * H;
    int j = 0;
    for (; j + 4 <= n; j += 4) {
        int s[4]; V rv[4]; float w[4];
#pragma unroll
        for (int u = 0; u < 4; u++) { int jj = j + u; s[u] = (jj < deg) ? csr[beg + jj] : d; }
#pragma unroll
        for (int u = 0; u < 4; u++) rv[u] = *(const V*)&hs[(size_t)s[u] * (H * 64) + rowoff];
#pragma unroll
        for (int u = 0; u < 4; u++) {
            float a = es[(size_t)s[u] * H + hB] + edhB;
            a = (a > 0.0f) ? a : 0.2f * a;
            w[u] = expf(a - mB) * invB;
        }
#pragma unroll
        for (int u = 0; u < 4; u++)
#pragma unroll
            for (int k = 0; k < H; k++) acc[k] += w[u] * bfu2f((unsigned short)rv[u][k]);
    }
    for (; j < n; j++) {
        int s = (j < deg) ? csr[beg + j] : d;
        V rv = *(const V*)&hs[(size_t)s * (H * 64) + rowoff];
        float a = es[(size_t)s * H + hB] + edhB;
        a = (a > 0.0f) ? a : 0.2f * a;
        float w = expf(a - mB) * invB;
#pragma unroll
        for (int k = 0; k < H; k++) acc[k] += w * bfu2f((unsigned short)rv[k]);
    }
    // ---- epilogue ----
#pragma unroll
    for (int k = 0; k < H; k++) {
        float v = acc[k];
        if (ELU) {
            v += bias[lane * H + k];
            v = (v > 0.0f) ? v : expm1f(v);
        }
        acc[k] = v;
    }
    float* op = out + (size_t)d * (H * 64) + rowoff;
#pragma unroll
    for (int q = 0; q < H / 4; q++)
        *(float4*)&op[q * 4] = *(float4*)&acc[q * 4];
}

// ---------- final ----------
__global__ void final_kernel(const float* __restrict__ acc2, const float* __restrict__ bias2,
                             const float* __restrict__ fbuf, const float* __restrict__ flat_b,
                             const float* __restrict__ last, const float* __restrict__ outW,
                             const float* __restrict__ outb, float* __restrict__ out, int N) {
    int n = blockIdx.x * blockDim.x + threadIdx.x;
    if (n >= N) return;
    float s = outb[0];
    const float* a = acc2 + (size_t)n * 256;
    for (int c = 0; c < 64; c++) {
        float h2 = 0.25f * (a[c] + a[64 + c] + a[128 + c] + a[192 + c]) + bias2[c];
        s += h2 * outW[c];
        s += (fbuf[(size_t)n * 64 + c] + flat_b[c]) * outW[64 + c];
        s += last[(size_t)n * 64 + c] * outW[128 + c];
    }
    out[n] = s;
}

// ---------- graph/model dims ----------
#define N1 80000
#define N2 16000
#define N3 4096
#define E1 256000
#define E2 65536

extern "C" void kernel_launch(void* const* d_in, const int* in_sizes, int n_in,
                              void* d_out, int out_size, void* d_ws, size_t ws_size,
                              hipStream_t stream) {
    const float* x    = (const float*)d_in[0];
    const float* flat = (const float*)d_in[1];
    const float* last = (const float*)d_in[2];
    const int*  es1i  = (const int*)d_in[3];
    const int*  ed1i  = (const int*)d_in[4];
    const int*  es2i  = (const int*)d_in[5];
    const int*  ed2i  = (const int*)d_in[6];
    const float* W1s  = (const float*)d_in[7];
    const float* W1d  = (const float*)d_in[8];
    const float* a1s  = (const float*)d_in[9];
    const float* a1d  = (const float*)d_in[10];
    const float* b1   = (const float*)d_in[11];
    const float* W2s  = (const float*)d_in[12];
    const float* W2d  = (const float*)d_in[13];
    const float* a2s  = (const float*)d_in[14];
    const float* a2d  = (const float*)d_in[15];
    const float* b2   = (const float*)d_in[16];
    const float* fW   = (const float*)d_in[17];
    const float* fb   = (const float*)d_in[18];
    const float* oW   = (const float*)d_in[19];
    const float* ob   = (const float*)d_in[20];
    float* out = (float*)d_out;

    float* ws = (float*)d_ws;
    // ---- layout (float-element offsets) ----
    unsigned short* hs1_bf = (unsigned short*)ws;                  // 40,960,000 us
    unsigned short* hd1_bf = (unsigned short*)(ws + 20480000);     //  8,192,000 us
    float* es1f = ws + 24576000;                                   // 640,000
    float* ed1f = ws + 25216000;                                   // 128,000
    float* acc1 = ws + 25344000;                                   // 8,192,000 -> 33,536,000
    unsigned short* x_hi = (unsigned short*)(ws + 33536000);
    unsigned short* x_lo = (unsigned short*)(ws + 43776000);
    unsigned short* a2h  = (unsigned short*)(ws + 33536000);       // aliases dead x region
    unsigned short* a2l  = (unsigned short*)(ws + 37632000);
    unsigned short* f_hi = (unsigned short*)(ws + 41728000);
    unsigned short* f_lo = (unsigned short*)(ws + 41990144);
    unsigned short* wb = (unsigned short*)(ws + 54016000);
    unsigned short* w1s_hi = wb;
    unsigned short* w1s_lo = wb + 131072;
    unsigned short* w1d_hi = wb + 262144;
    unsigned short* w1d_lo = wb + 393216;
    unsigned short* w2s_hi = wb + 524288;
    unsigned short* w2s_lo = wb + 655360;
    unsigned short* w2d_hi = wb + 786432;
    unsigned short* w2d_lo = wb + 917504;
    unsigned short* fw_t3  = wb + 1048576;
    int* ibase   = (int*)(ws + 54816000);
    int* cnt1    = ibase;
    int* cursor1 = ibase + 16000;
    int* cnt2    = ibase + 32000;
    int* cursor2 = ibase + 36096;
    int* start1  = ibase + 40192;
    int* start2  = ibase + 56193;
    int* csr1    = ibase + 60290;
    int* csr2    = ibase + 316290;
    const size_t NEED = ((size_t)54816000 + 381826) * 4;
    if (ws_size < NEED) {
        fprintf(stderr, "kernel_launch: ws_size %zu < needed %zu\n", ws_size, NEED);
        return;
    }
    unsigned short* hs2_bf = (unsigned short*)ws;
    unsigned short* hd2_bf = (unsigned short*)(ws + 2048000);
    float* es2f = ws + 2572288;
    float* ed2f = ws + 2636288;
    float* acc2 = ws + 2652672;
    float* fbuf = ws + 3701248;

    // ---- prep: splits + CSR ----
    split8_kernel<<<2048, 256, 0, stream>>>(x, x_hi, x_lo, (size_t)N1 * 256 / 8);
    wsplit2_kernel<<<(256 * 512 + 255) / 256, 256, 0, stream>>>(W1s, w1s_hi, w1s_lo, 256, 512);
    wsplit2_kernel<<<(256 * 512 + 255) / 256, 256, 0, stream>>>(W1d, w1d_hi, w1d_lo, 256, 512);
    wsplit2_kernel<<<(512 * 256 + 255) / 256, 256, 0, stream>>>(W2s, w2s_hi, w2s_lo, 512, 256);
    wsplit2_kernel<<<(512 * 256 + 255) / 256, 256, 0, stream>>>(W2d, w2d_hi, w2d_lo, 512, 256);
    wsplit_kernel<<<(128 * 64 + 255) / 256, 256, 0, stream>>>(fW, fw_t3, 128, 64);
    zeroi_kernel<<<160, 256, 0, stream>>>(ibase, 40192);
    hist_kernel<<<(E1 + 255) / 256, 256, 0, stream>>>(ed1i, E1, cnt1, N2);
    scan_kernel<<<1, 1024, 0, stream>>>(cnt1, start1, N2);
    fill_kernel<<<(E1 + 255) / 256, 256, 0, stream>>>(es1i, ed1i, E1, start1, cursor1, csr1, N2, N1);
    hist_kernel<<<(E2 + 255) / 256, 256, 0, stream>>>(ed2i, E2, cnt2, N3);
    scan_kernel<<<1, 1024, 0, stream>>>(cnt2, start2, N3);
    fill_kernel<<<(E2 + 255) / 256, 256, 0, stream>>>(es2i, ed2i, E2, start2, cursor2, csr2, N3, N2);

    // ---- layer 1 (es fused into GEMM epilogue) ----
    gemm_mfma2<<<dim3(2, N1 / 64), 256, 0, stream>>>(x_hi, x_lo, w1s_hi, w1s_lo, hs1_bf,
                                                     N1, 512, 256, a1s, es1f, 8);
    gemm_mfma2<<<dim3(2, N2 / 64), 256, 0, stream>>>(x_hi, x_lo, w1d_hi, w1d_lo, hd1_bf,
                                                     N2, 512, 256, a1d, ed1f, 8);
    gat_agg2<8, true><<<N2 / 4, 256, 0, stream>>>(csr1, start1, hs1_bf, es1f, ed1f, b1, acc1, N2);

    // ---- layer 2 ----
    split8_kernel<<<2048, 256, 0, stream>>>(acc1, a2h, a2l, (size_t)N2 * 512 / 8);
    gemm_mfma2<<<dim3(1, N2 / 64), 256, 0, stream>>>(a2h, a2l, w2s_hi, w2s_lo, hs2_bf,
                                                     N2, 256, 512, a2s, es2f, 4);
    gemm_mfma2<<<dim3(1, N3 / 64), 256, 0, stream>>>(a2h, a2l, w2d_hi, w2d_lo, hd2_bf,
                                                     N3, 256, 512, a2d, ed2f, 4);
    gat_agg2<4, false><<<N3 / 4, 256, 0, stream>>>(csr2, start2, hs2_bf, es2f, ed2f, nullptr, acc2, N3);

    // ---- flat MLP + output ----
    split8_kernel<<<512, 256, 0, stream>>>(flat, f_hi, f_lo, (size_t)N3 * 128 / 8);
    gemm_mfma<float><<<dim3(1, N3 / 64), 256, 0, stream>>>(f_hi, f_lo, fw_t3, fbuf, N3, 64, 128);
    final_kernel<<<(N3 + 255) / 256, 256, 0, stream>>>(acc2, b2, fbuf, fb, last, oW, ob, out, N3);
}

// Round 9
// 479.058 us; speedup vs baseline: 2.7748x; 1.0898x over previous
//
#include <hip/hip_runtime.h>
#include <hip/hip_bf16.h>
#include <cstdio>

typedef __attribute__((ext_vector_type(8))) short short8;
typedef __attribute__((ext_vector_type(4))) short short4v;
typedef __attribute__((ext_vector_type(4))) float f32x4;

template <int H> struct VecT;
template <> struct VecT<8> { using T = short8; };
template <> struct VecT<4> { using T = short4v; };

// ---------- bf16 helpers ----------
__device__ __forceinline__ float bfu2f(unsigned short u) {
    return __uint_as_float(((unsigned)u) << 16);
}
__device__ __forceinline__ unsigned short f2bfu(float f) {   // RNE
    __hip_bfloat16 b = __float2bfloat16(f);
    union { __hip_bfloat16 b; unsigned short u; } cv; cv.b = b;
    return cv.u;
}
__device__ __forceinline__ void store_out(float* p, float v) { *p = v; }
__device__ __forceinline__ void store_out(unsigned short* p, float v) { *p = f2bfu(v); }

// ---------- fills ----------
__global__ void zeroi_kernel(int* __restrict__ p, int n) {
    int i = blockIdx.x * blockDim.x + threadIdx.x;
    int stride = gridDim.x * blockDim.x;
    for (; i < n; i += stride) p[i] = 0;
}

// ---------- CSR build (both graphs in one launch) ----------
__global__ void hist_dual(const int* __restrict__ d1, int E1_, int* __restrict__ c1, int Nd1,
                          const int* __restrict__ d2, int E2_, int* __restrict__ c2, int Nd2) {
    int i = blockIdx.x * blockDim.x + threadIdx.x;
    if (i < E1_) {
        int d = d1[i];
        if ((unsigned)d < (unsigned)Nd1) atomicAdd(&c1[d], 1);
    } else if (i < E1_ + E2_) {
        int d = d2[i - E1_];
        if ((unsigned)d < (unsigned)Nd2) atomicAdd(&c2[d], 1);
    }
}
__global__ __launch_bounds__(1024)
void scan_dual(const int* __restrict__ c1, int* __restrict__ s1, int Nd1,
               const int* __restrict__ c2, int* __restrict__ s2, int Nd2) {
    const int* cnt = (blockIdx.x == 0) ? c1 : c2;
    int* start = (blockIdx.x == 0) ? s1 : s2;
    int Nd = (blockIdx.x == 0) ? Nd1 : Nd2;
    __shared__ int part[1024];
    int t = threadIdx.x;
    int k = (Nd + 1023) >> 10;
    int lo = t * k, hi = min(lo + k, Nd);
    if (lo > Nd) lo = Nd;
    int s = 0;
    for (int i = lo; i < hi; i++) s += cnt[i];
    part[t] = s;
    __syncthreads();
    for (int off = 1; off < 1024; off <<= 1) {
        int v = (t >= off) ? part[t - off] : 0;
        __syncthreads();
        part[t] += v;
        __syncthreads();
    }
    int run = (t > 0) ? part[t - 1] : 0;
    for (int i = lo; i < hi; i++) { start[i] = run; run += cnt[i]; }
    if (t == 1023) start[Nd] = part[1023];
}
__global__ void fill_dual(const int* __restrict__ sa1, const int* __restrict__ da1, int E1_,
                          const int* __restrict__ st1, int* __restrict__ cu1,
                          int* __restrict__ cs1, int Nd1, int Ns1,
                          const int* __restrict__ sa2, const int* __restrict__ da2, int E2_,
                          const int* __restrict__ st2, int* __restrict__ cu2,
                          int* __restrict__ cs2, int Nd2, int Ns2) {
    int i = blockIdx.x * blockDim.x + threadIdx.x;
    const int *sa, *da, *st;
    int *cu, *cs;
    int Nd, Ns, e;
    if (i < E1_) { sa = sa1; da = da1; st = st1; cu = cu1; cs = cs1; Nd = Nd1; Ns = Ns1; e = i; }
    else if (i < E1_ + E2_) { sa = sa2; da = da2; st = st2; cu = cu2; cs = cs2; Nd = Nd2; Ns = Ns2; e = i - E1_; }
    else return;
    int d = da[e];
    if ((unsigned)d >= (unsigned)Nd) return;
    int p = atomicAdd(&cu[d], 1);
    int idx = st[d] + p;
    if (idx >= st[d + 1]) return;
    int s = sa[e];
    if ((unsigned)s >= (unsigned)Ns) s = 0;
    cs[idx] = s;
}

// ---------- weight splits: two W [K][N] fp32 -> hi/lo [N][K] in one launch ----------
__global__ void wsplit2_dual(const float* __restrict__ Wa, unsigned short* __restrict__ hia,
                             unsigned short* __restrict__ loa,
                             const float* __restrict__ Wb, unsigned short* __restrict__ hib,
                             unsigned short* __restrict__ lob, int K, int N) {
    int i = blockIdx.x * blockDim.x + threadIdx.x;
    int KN = K * N;
    const float* W; unsigned short *hi, *lo; int j;
    if (i < KN) { W = Wa; hi = hia; lo = loa; j = i; }
    else if (i < 2 * KN) { W = Wb; hi = hib; lo = lob; j = i - KN; }
    else return;
    int k = j / N, n = j - k * N;
    float v = W[j];
    unsigned short h = f2bfu(v);
    hi[(size_t)n * K + k] = h;
    lo[(size_t)n * K + k] = f2bfu(v - bfu2f(h));
}

// ---------- W [K][N] fp32 -> Bt3 [N][3K] = [hi|lo|hi] (flat GEMM) ----------
__global__ void wsplit_kernel(const float* __restrict__ W, unsigned short* __restrict__ Bt3,
                              int K, int N) {
    int i = blockIdx.x * blockDim.x + threadIdx.x;
    if (i >= K * N) return;
    int k = i / N, n = i - k * N;
    float v = W[(size_t)k * N + n];
    unsigned short h = f2bfu(v);
    unsigned short l = f2bfu(v - bfu2f(h));
    size_t base = (size_t)n * (3 * K);
    Bt3[base + k] = h;
    Bt3[base + K + k] = l;
    Bt3[base + 2 * K + k] = h;
}

// ---------- MAIN MFMA GEMM, 64x256 tile, fp32 A with in-kernel hi/lo split ----------
// es[row, head] = sum_c C_f32[row, head*64+c] * att[head*64+c]   (head = col/64)
__global__ __launch_bounds__(256, 3)
void gemm_mfma2(const float* __restrict__ A,
                const unsigned short* __restrict__ Bhi, const unsigned short* __restrict__ Blo,
                unsigned short* __restrict__ C, int M, int N, int K,
                const float* __restrict__ att, float* __restrict__ es_out, int H) {
    __shared__ unsigned short As[2][64][40];
    __shared__ unsigned short Bs[2][256][40];
    const int tid = threadIdx.x;
    const int wave = tid >> 6, lane = tid & 63;
    const int quad = lane >> 4, l15 = lane & 15;
    const int m0 = blockIdx.y * 64, n0 = blockIdx.x * 256;
    const int arow = tid >> 2, acol = (tid & 3) * 8;
    f32x4 acc[4][4] = {};
    for (int k0 = 0; k0 < K; k0 += 32) {
        // stage A: load fp32, split to hi/lo bf16 in-kernel
        {
            const float* ap = &A[(size_t)(m0 + arow) * K + k0 + acol];
            const float4 v0 = *(const float4*)ap;
            const float4 v1 = *(const float4*)(ap + 4);
            float va[8] = {v0.x, v0.y, v0.z, v0.w, v1.x, v1.y, v1.z, v1.w};
            short8 h8, l8;
#pragma unroll
            for (int j = 0; j < 8; j++) {
                unsigned short hh = f2bfu(va[j]);
                h8[j] = (short)hh;
                l8[j] = (short)f2bfu(va[j] - bfu2f(hh));
            }
            *(short8*)&As[0][arow][acol] = h8;
            *(short8*)&As[1][arow][acol] = l8;
        }
#pragma unroll
        for (int i = 0; i < 4; i++) {
            int brow = arow + 64 * i;
            *(short8*)&Bs[0][brow][acol] = *(const short8*)&Bhi[(size_t)(n0 + brow) * K + k0 + acol];
            *(short8*)&Bs[1][brow][acol] = *(const short8*)&Blo[(size_t)(n0 + brow) * K + k0 + acol];
        }
        __syncthreads();
        short8 ah[4], al[4];
#pragma unroll
        for (int t = 0; t < 4; t++) {
            ah[t] = *(const short8*)&As[0][t * 16 + l15][quad * 8];
            al[t] = *(const short8*)&As[1][t * 16 + l15][quad * 8];
        }
#pragma unroll
        for (int nt = 0; nt < 4; nt++) {
            short8 bh = *(const short8*)&Bs[0][wave * 64 + nt * 16 + l15][quad * 8];
            short8 bl = *(const short8*)&Bs[1][wave * 64 + nt * 16 + l15][quad * 8];
#pragma unroll
            for (int mt = 0; mt < 4; mt++) {
                acc[mt][nt] = __builtin_amdgcn_mfma_f32_16x16x32_bf16(ah[mt], bh, acc[mt][nt], 0, 0, 0);
                acc[mt][nt] = __builtin_amdgcn_mfma_f32_16x16x32_bf16(ah[mt], bl, acc[mt][nt], 0, 0, 0);
                acc[mt][nt] = __builtin_amdgcn_mfma_f32_16x16x32_bf16(al[mt], bh, acc[mt][nt], 0, 0, 0);
            }
        }
        __syncthreads();
    }
#pragma unroll
    for (int mt = 0; mt < 4; mt++)
#pragma unroll
        for (int nt = 0; nt < 4; nt++)
#pragma unroll
            for (int r = 0; r < 4; r++) {
                int row = m0 + mt * 16 + quad * 4 + r;
                int col = n0 + wave * 64 + nt * 16 + l15;
                C[(size_t)row * N + col] = f2bfu(acc[mt][nt][r]);
            }
    if (att != nullptr) {
        const int head = (n0 >> 6) + wave;
        float av[4];
#pragma unroll
        for (int nt = 0; nt < 4; nt++) av[nt] = att[head * 64 + nt * 16 + l15];
#pragma unroll
        for (int mt = 0; mt < 4; mt++)
#pragma unroll
            for (int r = 0; r < 4; r++) {
                float p = acc[mt][0][r] * av[0] + acc[mt][1][r] * av[1]
                        + acc[mt][2][r] * av[2] + acc[mt][3][r] * av[3];
#pragma unroll
                for (int off = 1; off < 16; off <<= 1) p += __shfl_xor(p, off);
                if (l15 == 0)
                    es_out[(size_t)(m0 + mt * 16 + quad * 4 + r) * H + head] = p;
            }
    }
}

// ---------- small MFMA GEMM (64x64 tile, Bt3 layout, fp32 A in-kernel split) — flat only ----------
// Requires K%64==0.
__global__ __launch_bounds__(256)
void gemm_mfma(const float* __restrict__ A, const unsigned short* __restrict__ Bt3,
               float* __restrict__ C, int M, int N, int K) {
    const int KK = 3 * K;
    __shared__ unsigned short As[2][64][72];
    __shared__ unsigned short Bs[64][72];
    const int tid = threadIdx.x;
    const int wave = tid >> 6, lane = tid & 63;
    const int wr = wave >> 1, wc = wave & 1;
    const int quad = lane >> 4, l15 = lane & 15;
    const int m0 = blockIdx.y * 64, n0 = blockIdx.x * 64;
    f32x4 acc[2][2] = {};
    for (int k0 = 0; k0 < KK; k0 += 64) {
        const int seg = k0 / K;
        const int ks = k0 - seg * K;
#pragma unroll
        for (int i = 0; i < 2; i++) {
            int idx = tid + i * 256;
            int r = idx >> 3, cv = (idx & 7) * 8;
            const float* ap = &A[(size_t)(m0 + r) * K + ks + cv];
            const float4 v0 = *(const float4*)ap;
            const float4 v1 = *(const float4*)(ap + 4);
            float va[8] = {v0.x, v0.y, v0.z, v0.w, v1.x, v1.y, v1.z, v1.w};
            short8 h8, l8;
#pragma unroll
            for (int j = 0; j < 8; j++) {
                unsigned short hh = f2bfu(va[j]);
                h8[j] = (short)hh;
                l8[j] = (short)f2bfu(va[j] - bfu2f(hh));
            }
            *(short8*)&As[0][r][cv] = h8;
            *(short8*)&As[1][r][cv] = l8;
            *(short8*)&Bs[r][cv] = *(const short8*)&Bt3[(size_t)(n0 + r) * KK + k0 + cv];
        }
        __syncthreads();
        const int abank = (seg < 2) ? 0 : 1;
#pragma unroll
        for (int kk = 0; kk < 64; kk += 32) {
            short8 a[2], b[2];
#pragma unroll
            for (int t = 0; t < 2; t++) {
                a[t] = *(const short8*)&As[abank][wr * 32 + t * 16 + l15][kk + quad * 8];
                b[t] = *(const short8*)&Bs[wc * 32 + t * 16 + l15][kk + quad * 8];
            }
#pragma unroll
            for (int mt = 0; mt < 2; mt++)
#pragma unroll
                for (int nt = 0; nt < 2; nt++)
                    acc[mt][nt] = __builtin_amdgcn_mfma_f32_16x16x32_bf16(
                        a[mt], b[nt], acc[mt][nt], 0, 0, 0);
        }
        __syncthreads();
    }
#pragma unroll
    for (int mt = 0; mt < 2; mt++)
#pragma unroll
        for (int nt = 0; nt < 2; nt++)
#pragma unroll
            for (int r = 0; r < 4; r++) {
                int row = m0 + wr * 32 + mt * 16 + quad * 4 + r;
                int col = n0 + wc * 32 + nt * 16 + l15;
                C[(size_t)row * N + col] = acc[mt][nt][r];
            }
}

// ---------- GAT aggregate v2: one WAVE per dst node, all heads; coalesced row gathers ----------
template <int H, bool ELU>
__global__ __launch_bounds__(256)
void gat_agg2(const int* __restrict__ csr, const int* __restrict__ rs,
              const unsigned short* __restrict__ hs,  // [Ns, H*64] bf16
              const float* __restrict__ es,           // [Ns, H]
              const float* __restrict__ ed,           // [Nd, H]
              const float* __restrict__ bias,         // [H*64] or null
              float* __restrict__ out,                // [Nd, H*64] fp32
              int Nd) {
    constexpr int LH = (H == 8) ? 3 : 2;
    constexpr int EPC = 64 >> LH;
    const int lane = threadIdx.x & 63;
    const int d = blockIdx.x * (blockDim.x >> 6) + (threadIdx.x >> 6);
    if (d >= Nd) return;
    const int beg = rs[d];
    const int deg = rs[d + 1] - beg;
    const int n = deg + 1;
    const int h = lane & (H - 1);
    const int e0 = lane >> LH;
    const float edh = ed[(size_t)d * H + h];
    float mx = -1e30f;
    for (int j0 = 0; j0 < n; j0 += EPC) {
        int j = j0 + e0;
        if (j < n) {
            int s = (j < deg) ? csr[beg + j] : d;
            float a = es[(size_t)s * H + h] + edh;
            a = (a > 0.0f) ? a : 0.2f * a;
            mx = fmaxf(mx, a);
        }
    }
#pragma unroll
    for (int off = H; off < 64; off <<= 1) mx = fmaxf(mx, __shfl_xor(mx, off));
    float den = 0.0f;
    for (int j0 = 0; j0 < n; j0 += EPC) {
        int j = j0 + e0;
        if (j < n) {
            int s = (j < deg) ? csr[beg + j] : d;
            float a = es[(size_t)s * H + h] + edh;
            a = (a > 0.0f) ? a : 0.2f * a;
            den += expf(a - mx);
        }
    }
#pragma unroll
    for (int off = H; off < 64; off <<= 1) den += __shfl_xor(den, off);
    const float inv = 1.0f / den;
    const int hB = lane >> (6 - LH);
    const float mB = __shfl(mx, hB);
    const float invB = __shfl(inv, hB);
    const float edhB = __shfl(edh, hB);
    using V = typename VecT<H>::T;
    float acc[H] = {};
    const size_t rowoff = (size_t)lane * H;
    int j = 0;
    for (; j + 4 <= n; j += 4) {
        int s[4]; V rv[4]; float w[4];
#pragma unroll
        for (int u = 0; u < 4; u++) { int jj = j + u; s[u] = (jj < deg) ? csr[beg + jj] : d; }
#pragma unroll
        for (int u = 0; u < 4; u++) rv[u] = *(const V*)&hs[(size_t)s[u] * (H * 64) + rowoff];
#pragma unroll
        for (int u = 0; u < 4; u++) {
            float a = es[(size_t)s[u] * H + hB] + edhB;
            a = (a > 0.0f) ? a : 0.2f * a;
            w[u] = expf(a - mB) * invB;
        }
#pragma unroll
        for (int u = 0; u < 4; u++)
#pragma unroll
            for (int k = 0; k < H; k++) acc[k] += w[u] * bfu2f((unsigned short)rv[u][k]);
    }
    for (; j < n; j++) {
        int s = (j < deg) ? csr[beg + j] : d;
        V rv = *(const V*)&hs[(size_t)s * (H * 64) + rowoff];
        float a = es[(size_t)s * H + hB] + edhB;
        a = (a > 0.0f) ? a : 0.2f * a;
        float w = expf(a - mB) * invB;
#pragma unroll
        for (int k = 0; k < H; k++) acc[k] += w * bfu2f((unsigned short)rv[k]);
    }
#pragma unroll
    for (int k = 0; k < H; k++) {
        float v = acc[k];
        if (ELU) {
            v += bias[lane * H + k];
            v = (v > 0.0f) ? v : expm1f(v);
        }
        acc[k] = v;
    }
    float* op = out + (size_t)d * (H * 64) + rowoff;
#pragma unroll
    for (int q = 0; q < H / 4; q++)
        *(float4*)&op[q * 4] = *(float4*)&acc[q * 4];
}

// ---------- final ----------
__global__ void final_kernel(const float* __restrict__ acc2, const float* __restrict__ bias2,
                             const float* __restrict__ fbuf, const float* __restrict__ flat_b,
                             const float* __restrict__ last, const float* __restrict__ outW,
                             const float* __restrict__ outb, float* __restrict__ out, int N) {
    int n = blockIdx.x * blockDim.x + threadIdx.x;
    if (n >= N) return;
    float s = outb[0];
    const float* a = acc2 + (size_t)n * 256;
    for (int c = 0; c < 64; c++) {
        float h2 = 0.25f * (a[c] + a[64 + c] + a[128 + c] + a[192 + c]) + bias2[c];
        s += h2 * outW[c];
        s += (fbuf[(size_t)n * 64 + c] + flat_b[c]) * outW[64 + c];
        s += last[(size_t)n * 64 + c] * outW[128 + c];
    }
    out[n] = s;
}

// ---------- graph/model dims ----------
#define N1 80000
#define N2 16000
#define N3 4096
#define E1 256000
#define E2 65536

extern "C" void kernel_launch(void* const* d_in, const int* in_sizes, int n_in,
                              void* d_out, int out_size, void* d_ws, size_t ws_size,
                              hipStream_t stream) {
    const float* x    = (const float*)d_in[0];
    const float* flat = (const float*)d_in[1];
    const float* last = (const float*)d_in[2];
    const int*  es1i  = (const int*)d_in[3];
    const int*  ed1i  = (const int*)d_in[4];
    const int*  es2i  = (const int*)d_in[5];
    const int*  ed2i  = (const int*)d_in[6];
    const float* W1s  = (const float*)d_in[7];
    const float* W1d  = (const float*)d_in[8];
    const float* a1s  = (const float*)d_in[9];
    const float* a1d  = (const float*)d_in[10];
    const float* b1   = (const float*)d_in[11];
    const float* W2s  = (const float*)d_in[12];
    const float* W2d  = (const float*)d_in[13];
    const float* a2s  = (const float*)d_in[14];
    const float* a2d  = (const float*)d_in[15];
    const float* b2   = (const float*)d_in[16];
    const float* fW   = (const float*)d_in[17];
    const float* fb   = (const float*)d_in[18];
    const float* oW   = (const float*)d_in[19];
    const float* ob   = (const float*)d_in[20];
    float* out = (float*)d_out;

    float* ws = (float*)d_ws;
    // ---- layout (float-element offsets; same proven footprint as R8) ----
    unsigned short* hs1_bf = (unsigned short*)ws;                  // 40,960,000 us
    unsigned short* hd1_bf = (unsigned short*)(ws + 20480000);     //  8,192,000 us
    float* es1f = ws + 24576000;                                   // 640,000
    float* ed1f = ws + 25216000;                                   // 128,000
    float* acc1 = ws + 25344000;                                   // 8,192,000 -> 33,536,000
    unsigned short* wb = (unsigned short*)(ws + 54016000);
    unsigned short* w1s_hi = wb;
    unsigned short* w1s_lo = wb + 131072;
    unsigned short* w1d_hi = wb + 262144;
    unsigned short* w1d_lo = wb + 393216;
    unsigned short* w2s_hi = wb + 524288;
    unsigned short* w2s_lo = wb + 655360;
    unsigned short* w2d_hi = wb + 786432;
    unsigned short* w2d_lo = wb + 917504;
    unsigned short* fw_t3  = wb + 1048576;
    int* ibase   = (int*)(ws + 54816000);
    int* cnt1    = ibase;
    int* cursor1 = ibase + 16000;
    int* cnt2    = ibase + 32000;
    int* cursor2 = ibase + 36096;
    int* start1  = ibase + 40192;
    int* start2  = ibase + 56193;
    int* csr1    = ibase + 60290;
    int* csr2    = ibase + 316290;
    const size_t NEED = ((size_t)54816000 + 381826) * 4;
    if (ws_size < NEED) {
        fprintf(stderr, "kernel_launch: ws_size %zu < needed %zu\n", ws_size, NEED);
        return;
    }
    unsigned short* hs2_bf = (unsigned short*)ws;
    unsigned short* hd2_bf = (unsigned short*)(ws + 2048000);
    float* es2f = ws + 2572288;
    float* ed2f = ws + 2636288;
    float* acc2 = ws + 2652672;
    float* fbuf = ws + 3701248;

    // ---- prep: weight splits + CSR (dual-graph launches) ----
    wsplit2_dual<<<(2 * 131072 + 255) / 256, 256, 0, stream>>>(
        W1s, w1s_hi, w1s_lo, W1d, w1d_hi, w1d_lo, 256, 512);
    wsplit2_dual<<<(2 * 131072 + 255) / 256, 256, 0, stream>>>(
        W2s, w2s_hi, w2s_lo, W2d, w2d_hi, w2d_lo, 512, 256);
    wsplit_kernel<<<(128 * 64 + 255) / 256, 256, 0, stream>>>(fW, fw_t3, 128, 64);
    zeroi_kernel<<<160, 256, 0, stream>>>(ibase, 40192);
    hist_dual<<<(E1 + E2 + 255) / 256, 256, 0, stream>>>(ed1i, E1, cnt1, N2, ed2i, E2, cnt2, N3);
    scan_dual<<<2, 1024, 0, stream>>>(cnt1, start1, N2, cnt2, start2, N3);
    fill_dual<<<(E1 + E2 + 255) / 256, 256, 0, stream>>>(
        es1i, ed1i, E1, start1, cursor1, csr1, N2, N1,
        es2i, ed2i, E2, start2, cursor2, csr2, N3, N2);

    // ---- layer 1 (fp32 A in-kernel split; es fused into GEMM epilogue) ----
    gemm_mfma2<<<dim3(2, N1 / 64), 256, 0, stream>>>(x, w1s_hi, w1s_lo, hs1_bf,
                                                     N1, 512, 256, a1s, es1f, 8);
    gemm_mfma2<<<dim3(2, N2 / 64), 256, 0, stream>>>(x, w1d_hi, w1d_lo, hd1_bf,
                                                     N2, 512, 256, a1d, ed1f, 8);
    gat_agg2<8, true><<<N2 / 4, 256, 0, stream>>>(csr1, start1, hs1_bf, es1f, ed1f, b1, acc1, N2);

    // ---- layer 2 (fp32 acc1 read directly) ----
    gemm_mfma2<<<dim3(1, N2 / 64), 256, 0, stream>>>(acc1, w2s_hi, w2s_lo, hs2_bf,
                                                     N2, 256, 512, a2s, es2f, 4);
    gemm_mfma2<<<dim3(1, N3 / 64), 256, 0, stream>>>(acc1, w2d_hi, w2d_lo, hd2_bf,
                                                     N3, 256, 512, a2d, ed2f, 4);
    gat_agg2<4, false><<<N3 / 4, 256, 0, stream>>>(csr2, start2, hs2_bf, es2f, ed2f, nullptr, acc2, N3);

    // ---- flat MLP + output ----
    gemm_mfma<<<dim3(1, N3 / 64), 256, 0, stream>>>(flat, fw_t3, fbuf, N3, 64, 128);
    final_kernel<<<(N3 + 255) / 256, 256, 0, stream>>>(acc2, b2, fbuf, fb, last, oW, ob, out, N3);
}

// Round 10
// 471.735 us; speedup vs baseline: 2.8179x; 1.0155x over previous
//
#include <hip/hip_runtime.h>
#include <hip/hip_bf16.h>
#include <cstdio>

typedef __attribute__((ext_vector_type(8))) short short8;
typedef __attribute__((ext_vector_type(4))) short short4v;
typedef __attribute__((ext_vector_type(4))) float f32x4;

template <int H> struct VecT;
template <> struct VecT<8> { using T = short8; };
template <> struct VecT<4> { using T = short4v; };

// ---------- bf16 helpers ----------
__device__ __forceinline__ float bfu2f(unsigned short u) {
    return __uint_as_float(((unsigned)u) << 16);
}
__device__ __forceinline__ unsigned short f2bfu(float f) {   // RNE
    __hip_bfloat16 b = __float2bfloat16(f);
    union { __hip_bfloat16 b; unsigned short u; } cv; cv.b = b;
    return cv.u;
}

// ---------- graph/model dims ----------
#define N1 80000
#define N2 16000
#define N3 4096
#define E1 256000
#define E2 65536

// ---------- fused prep: all weight splits + int zeroing in one launch ----------
// seg0: W1s|W1d (K=256,N=512) -> hi/lo [N][K]     (2*131072 items)
// seg1: W2s|W2d (K=512,N=256) -> hi/lo [N][K]     (2*131072 items)
// seg2: fW (K=128,N=64) -> Bt3 [N][3K]            (8192 items)
// seg3: zero ints                                  (zn items)
__global__ void prep_kernel(const float* __restrict__ W1s, const float* __restrict__ W1d,
                            unsigned short* __restrict__ w1s_hi, unsigned short* __restrict__ w1s_lo,
                            unsigned short* __restrict__ w1d_hi, unsigned short* __restrict__ w1d_lo,
                            const float* __restrict__ W2s, const float* __restrict__ W2d,
                            unsigned short* __restrict__ w2s_hi, unsigned short* __restrict__ w2s_lo,
                            unsigned short* __restrict__ w2d_hi, unsigned short* __restrict__ w2d_lo,
                            const float* __restrict__ fW, unsigned short* __restrict__ fw_t3,
                            int* __restrict__ zbase, int zn) {
    int i = blockIdx.x * blockDim.x + threadIdx.x;
    const int S0 = 262144, S1 = 262144, S2 = 8192;
    if (i < S0) {
        const float* W = (i < 131072) ? W1s : W1d;
        unsigned short* hi = (i < 131072) ? w1s_hi : w1d_hi;
        unsigned short* lo = (i < 131072) ? w1s_lo : w1d_lo;
        int j = i & 131071;
        int k = j >> 9, n = j & 511;            // K=256, N=512
        float v = W[j];
        unsigned short h = f2bfu(v);
        hi[(size_t)n * 256 + k] = h;
        lo[(size_t)n * 256 + k] = f2bfu(v - bfu2f(h));
    } else if (i < S0 + S1) {
        int ii = i - S0;
        const float* W = (ii < 131072) ? W2s : W2d;
        unsigned short* hi = (ii < 131072) ? w2s_hi : w2d_hi;
        unsigned short* lo = (ii < 131072) ? w2s_lo : w2d_lo;
        int j = ii & 131071;
        int k = j >> 8, n = j & 255;            // K=512, N=256
        float v = W[j];
        unsigned short h = f2bfu(v);
        hi[(size_t)n * 512 + k] = h;
        lo[(size_t)n * 512 + k] = f2bfu(v - bfu2f(h));
    } else if (i < S0 + S1 + S2) {
        int j = i - S0 - S1;
        int k = j >> 6, n = j & 63;             // K=128, N=64
        float v = fW[j];
        unsigned short h = f2bfu(v);
        unsigned short l = f2bfu(v - bfu2f(h));
        size_t base = (size_t)n * 384;
        fw_t3[base + k] = h;
        fw_t3[base + 128 + k] = l;
        fw_t3[base + 256 + k] = h;
    } else {
        int j = i - S0 - S1 - S2;
        if (j < zn) zbase[j] = 0;
    }
}

// ---------- CSR build (both graphs per launch) ----------
__global__ void hist_dual(const int* __restrict__ d1, int* __restrict__ c1,
                          const int* __restrict__ d2, int* __restrict__ c2) {
    int i = blockIdx.x * blockDim.x + threadIdx.x;
    if (i < E1) {
        int d = d1[i];
        if ((unsigned)d < (unsigned)N2) atomicAdd(&c1[d], 1);
    } else if (i < E1 + E2) {
        int d = d2[i - E1];
        if ((unsigned)d < (unsigned)N3) atomicAdd(&c2[d], 1);
    }
}
__global__ __launch_bounds__(1024)
void scan_dual(const int* __restrict__ c1, int* __restrict__ s1, int Nd1,
               const int* __restrict__ c2, int* __restrict__ s2, int Nd2) {
    const int* cnt = (blockIdx.x == 0) ? c1 : c2;
    int* start = (blockIdx.x == 0) ? s1 : s2;
    int Nd = (blockIdx.x == 0) ? Nd1 : Nd2;
    __shared__ int part[1024];
    int t = threadIdx.x;
    int k = (Nd + 1023) >> 10;
    int lo = t * k, hi = min(lo + k, Nd);
    if (lo > Nd) lo = Nd;
    int s = 0;
    for (int i = lo; i < hi; i++) s += cnt[i];
    part[t] = s;
    __syncthreads();
    for (int off = 1; off < 1024; off <<= 1) {
        int v = (t >= off) ? part[t - off] : 0;
        __syncthreads();
        part[t] += v;
        __syncthreads();
    }
    int run = (t > 0) ? part[t - 1] : 0;
    for (int i = lo; i < hi; i++) { start[i] = run; run += cnt[i]; }
    if (t == 1023) start[Nd] = part[1023];
}
__global__ void fill_dual(const int* __restrict__ sa1, const int* __restrict__ da1,
                          const int* __restrict__ st1, int* __restrict__ cu1, int* __restrict__ cs1,
                          const int* __restrict__ sa2, const int* __restrict__ da2,
                          const int* __restrict__ st2, int* __restrict__ cu2, int* __restrict__ cs2) {
    int i = blockIdx.x * blockDim.x + threadIdx.x;
    const int *sa, *da, *st;
    int *cu, *cs;
    int Nd, Ns, e;
    if (i < E1) { sa = sa1; da = da1; st = st1; cu = cu1; cs = cs1; Nd = N2; Ns = N1; e = i; }
    else if (i < E1 + E2) { sa = sa2; da = da2; st = st2; cu = cu2; cs = cs2; Nd = N3; Ns = N2; e = i - E1; }
    else return;
    int d = da[e];
    if ((unsigned)d >= (unsigned)Nd) return;
    int p = atomicAdd(&cu[d], 1);
    int idx = st[d] + p;
    if (idx >= st[d + 1]) return;
    int s = sa[e];
    if ((unsigned)s >= (unsigned)Ns) s = 0;
    cs[idx] = s;
}

// ---------- FUSED MFMA GEMM: src+dst sub-GEMMs in one grid; B from registers ----------
// A [*,K] fp32 (in-kernel hi/lo split in LDS); B hi/lo [N][K] bf16 (global, L2-resident).
// grid.y in [0,Mb1) -> sub-GEMM 1, [Mb1, Mb1+Mb2) -> sub-GEMM 2. grid.x = N/256.
// Fused escore epilogue: es[row, head] = sum_c C_f32[row, head*64+c]*att[head*64+c].
__global__ __launch_bounds__(256, 4)
void gemm_fused(const float* __restrict__ A,
                const unsigned short* __restrict__ Bhi1, const unsigned short* __restrict__ Blo1,
                unsigned short* __restrict__ C1, const float* __restrict__ att1,
                float* __restrict__ es1,
                const unsigned short* __restrict__ Bhi2, const unsigned short* __restrict__ Blo2,
                unsigned short* __restrict__ C2, const float* __restrict__ att2,
                float* __restrict__ es2,
                int Mb1, int N, int K, int H) {
    __shared__ unsigned short As[2][64][40];
    const unsigned short *Bhi, *Blo;
    unsigned short* C;
    const float* att;
    float* es_out;
    int m0;
    if ((int)blockIdx.y < Mb1) {
        Bhi = Bhi1; Blo = Blo1; C = C1; att = att1; es_out = es1;
        m0 = blockIdx.y * 64;
    } else {
        Bhi = Bhi2; Blo = Blo2; C = C2; att = att2; es_out = es2;
        m0 = (blockIdx.y - Mb1) * 64;
    }
    const int tid = threadIdx.x;
    const int wave = tid >> 6, lane = tid & 63;
    const int quad = lane >> 4, l15 = lane & 15;
    const int n0 = blockIdx.x * 256;
    const int arow = tid >> 2, acol = (tid & 3) * 8;
    f32x4 acc[4][4] = {};
    for (int k0 = 0; k0 < K; k0 += 32) {
        // B fragments straight from global (L2-resident weights) — overlaps A staging
        short8 bh[4], bl[4];
#pragma unroll
        for (int nt = 0; nt < 4; nt++) {
            size_t boff = (size_t)(n0 + wave * 64 + nt * 16 + l15) * K + k0 + quad * 8;
            bh[nt] = *(const short8*)&Bhi[boff];
            bl[nt] = *(const short8*)&Blo[boff];
        }
        // stage A: fp32 load -> hi/lo bf16 split -> LDS
        {
            const float* ap = &A[(size_t)(m0 + arow) * K + k0 + acol];
            const float4 v0 = *(const float4*)ap;
            const float4 v1 = *(const float4*)(ap + 4);
            float va[8] = {v0.x, v0.y, v0.z, v0.w, v1.x, v1.y, v1.z, v1.w};
            short8 h8, l8;
#pragma unroll
            for (int j = 0; j < 8; j++) {
                unsigned short hh = f2bfu(va[j]);
                h8[j] = (short)hh;
                l8[j] = (short)f2bfu(va[j] - bfu2f(hh));
            }
            *(short8*)&As[0][arow][acol] = h8;
            *(short8*)&As[1][arow][acol] = l8;
        }
        __syncthreads();
#pragma unroll
        for (int mt = 0; mt < 4; mt++) {
            short8 ah = *(const short8*)&As[0][mt * 16 + l15][quad * 8];
            short8 al = *(const short8*)&As[1][mt * 16 + l15][quad * 8];
#pragma unroll
            for (int nt = 0; nt < 4; nt++) {
                acc[mt][nt] = __builtin_amdgcn_mfma_f32_16x16x32_bf16(ah, bh[nt], acc[mt][nt], 0, 0, 0);
                acc[mt][nt] = __builtin_amdgcn_mfma_f32_16x16x32_bf16(ah, bl[nt], acc[mt][nt], 0, 0, 0);
                acc[mt][nt] = __builtin_amdgcn_mfma_f32_16x16x32_bf16(al, bh[nt], acc[mt][nt], 0, 0, 0);
            }
        }
        __syncthreads();
    }
#pragma unroll
    for (int mt = 0; mt < 4; mt++)
#pragma unroll
        for (int nt = 0; nt < 4; nt++)
#pragma unroll
            for (int r = 0; r < 4; r++) {
                int row = m0 + mt * 16 + quad * 4 + r;
                int col = n0 + wave * 64 + nt * 16 + l15;
                C[(size_t)row * N + col] = f2bfu(acc[mt][nt][r]);
            }
    // fused escore (each wave owns one head's 64 cols)
    {
        const int head = (n0 >> 6) + wave;
        float av[4];
#pragma unroll
        for (int nt = 0; nt < 4; nt++) av[nt] = att[head * 64 + nt * 16 + l15];
#pragma unroll
        for (int mt = 0; mt < 4; mt++)
#pragma unroll
            for (int r = 0; r < 4; r++) {
                float p = acc[mt][0][r] * av[0] + acc[mt][1][r] * av[1]
                        + acc[mt][2][r] * av[2] + acc[mt][3][r] * av[3];
#pragma unroll
                for (int off = 1; off < 16; off <<= 1) p += __shfl_xor(p, off);
                if (l15 == 0)
                    es_out[(size_t)(m0 + mt * 16 + quad * 4 + r) * H + head] = p;
            }
    }
}

// ---------- small MFMA GEMM (64x64 tile, Bt3 layout, fp32 A in-kernel split) — flat only ----------
__global__ __launch_bounds__(256)
void gemm_mfma(const float* __restrict__ A, const unsigned short* __restrict__ Bt3,
               float* __restrict__ C, int M, int N, int K) {
    const int KK = 3 * K;
    __shared__ unsigned short As[2][64][72];
    __shared__ unsigned short Bs[64][72];
    const int tid = threadIdx.x;
    const int wave = tid >> 6, lane = tid & 63;
    const int wr = wave >> 1, wc = wave & 1;
    const int quad = lane >> 4, l15 = lane & 15;
    const int m0 = blockIdx.y * 64, n0 = blockIdx.x * 64;
    f32x4 acc[2][2] = {};
    for (int k0 = 0; k0 < KK; k0 += 64) {
        const int seg = k0 / K;
        const int ks = k0 - seg * K;
#pragma unroll
        for (int i = 0; i < 2; i++) {
            int idx = tid + i * 256;
            int r = idx >> 3, cv = (idx & 7) * 8;
            const float* ap = &A[(size_t)(m0 + r) * K + ks + cv];
            const float4 v0 = *(const float4*)ap;
            const float4 v1 = *(const float4*)(ap + 4);
            float va[8] = {v0.x, v0.y, v0.z, v0.w, v1.x, v1.y, v1.z, v1.w};
            short8 h8, l8;
#pragma unroll
            for (int j = 0; j < 8; j++) {
                unsigned short hh = f2bfu(va[j]);
                h8[j] = (short)hh;
                l8[j] = (short)f2bfu(va[j] - bfu2f(hh));
            }
            *(short8*)&As[0][r][cv] = h8;
            *(short8*)&As[1][r][cv] = l8;
            *(short8*)&Bs[r][cv] = *(const short8*)&Bt3[(size_t)(n0 + r) * KK + k0 + cv];
        }
        __syncthreads();
        const int abank = (seg < 2) ? 0 : 1;
#pragma unroll
        for (int kk = 0; kk < 64; kk += 32) {
            short8 a[2], b[2];
#pragma unroll
            for (int t = 0; t < 2; t++) {
                a[t] = *(const short8*)&As[abank][wr * 32 + t * 16 + l15][kk + quad * 8];
                b[t] = *(const short8*)&Bs[wc * 32 + t * 16 + l15][kk + quad * 8];
            }
#pragma unroll
            for (int mt = 0; mt < 2; mt++)
#pragma unroll
                for (int nt = 0; nt < 2; nt++)
                    acc[mt][nt] = __builtin_amdgcn_mfma_f32_16x16x32_bf16(
                        a[mt], b[nt], acc[mt][nt], 0, 0, 0);
        }
        __syncthreads();
    }
#pragma unroll
    for (int mt = 0; mt < 2; mt++)
#pragma unroll
        for (int nt = 0; nt < 2; nt++)
#pragma unroll
            for (int r = 0; r < 4; r++) {
                int row = m0 + wr * 32 + mt * 16 + quad * 4 + r;
                int col = n0 + wc * 32 + nt * 16 + l15;
                C[(size_t)row * N + col] = acc[mt][nt][r];
            }
}

// ---------- GAT aggregate: one WAVE per dst node, all heads; coalesced row gathers ----------
template <int H, bool ELU>
__global__ __launch_bounds__(256)
void gat_agg2(const int* __restrict__ csr, const int* __restrict__ rs,
              const unsigned short* __restrict__ hs,  // [Ns, H*64] bf16
              const float* __restrict__ es,           // [Ns, H]
              const float* __restrict__ ed,           // [Nd, H]
              const float* __restrict__ bias,         // [H*64] or null
              float* __restrict__ out,                // [Nd, H*64] fp32
              int Nd) {
    constexpr int LH = (H == 8) ? 3 : 2;
    constexpr int EPC = 64 >> LH;
    const int lane = threadIdx.x & 63;
    const int d = blockIdx.x * (blockDim.x >> 6) + (threadIdx.x >> 6);
    if (d >= Nd) return;
    const int beg = rs[d];
    const int deg = rs[d + 1] - beg;
    const int n = deg + 1;
    const int h = lane & (H - 1);
    const int e0 = lane >> LH;
    const float edh = ed[(size_t)d * H + h];
    float mx = -1e30f;
    for (int j0 = 0; j0 < n; j0 += EPC) {
        int j = j0 + e0;
        if (j < n) {
            int s = (j < deg) ? csr[beg + j] : d;
            float a = es[(size_t)s * H + h] + edh;
            a = (a > 0.0f) ? a : 0.2f * a;
            mx = fmaxf(mx, a);
        }
    }
#pragma unroll
    for (int off = H; off < 64; off <<= 1) mx = fmaxf(mx, __shfl_xor(mx, off));
    float den = 0.0f;
    for (int j0 = 0; j0 < n; j0 += EPC) {
        int j = j0 + e0;
        if (j < n) {
            int s = (j < deg) ? csr[beg + j] : d;
            float a = es[(size_t)s * H + h] + edh;
            a = (a > 0.0f) ? a : 0.2f * a;
            den += expf(a - mx);
        }
    }
#pragma unroll
    for (int off = H; off < 64; off <<= 1) den += __shfl_xor(den, off);
    const float inv = 1.0f / den;
    const int hB = lane >> (6 - LH);
    const float mB = __shfl(mx, hB);
    const float invB = __shfl(inv, hB);
    const float edhB = __shfl(edh, hB);
    using V = typename VecT<H>::T;
    float acc[H] = {};
    const size_t rowoff = (size_t)lane * H;
    int j = 0;
    for (; j + 4 <= n; j += 4) {
        int s[4]; V rv[4]; float w[4];
#pragma unroll
        for (int u = 0; u < 4; u++) { int jj = j + u; s[u] = (jj < deg) ? csr[beg + jj] : d; }
#pragma unroll
        for (int u = 0; u < 4; u++) rv[u] = *(const V*)&hs[(size_t)s[u] * (H * 64) + rowoff];
#pragma unroll
        for (int u = 0; u < 4; u++) {
            float a = es[(size_t)s[u] * H + hB] + edhB;
            a = (a > 0.0f) ? a : 0.2f * a;
            w[u] = expf(a - mB) * invB;
        }
#pragma unroll
        for (int u = 0; u < 4; u++)
#pragma unroll
            for (int k = 0; k < H; k++) acc[k] += w[u] * bfu2f((unsigned short)rv[u][k]);
    }
    for (; j < n; j++) {
        int s = (j < deg) ? csr[beg + j] : d;
        V rv = *(const V*)&hs[(size_t)s * (H * 64) + rowoff];
        float a = es[(size_t)s * H + hB] + edhB;
        a = (a > 0.0f) ? a : 0.2f * a;
        float w = expf(a - mB) * invB;
#pragma unroll
        for (int k = 0; k < H; k++) acc[k] += w * bfu2f((unsigned short)rv[k]);
    }
#pragma unroll
    for (int k = 0; k < H; k++) {
        float v = acc[k];
        if (ELU) {
            v += bias[lane * H + k];
            v = (v > 0.0f) ? v : expm1f(v);
        }
        acc[k] = v;
    }
    float* op = out + (size_t)d * (H * 64) + rowoff;
#pragma unroll
    for (int q = 0; q < H / 4; q++)
        *(float4*)&op[q * 4] = *(float4*)&acc[q * 4];
}

// ---------- final ----------
__global__ void final_kernel(const float* __restrict__ acc2, const float* __restrict__ bias2,
                             const float* __restrict__ fbuf, const float* __restrict__ flat_b,
                             const float* __restrict__ last, const float* __restrict__ outW,
                             const float* __restrict__ outb, float* __restrict__ out, int N) {
    int n = blockIdx.x * blockDim.x + threadIdx.x;
    if (n >= N) return;
    float s = outb[0];
    const float* a = acc2 + (size_t)n * 256;
    for (int c = 0; c < 64; c++) {
        float h2 = 0.25f * (a[c] + a[64 + c] + a[128 + c] + a[192 + c]) + bias2[c];
        s += h2 * outW[c];
        s += (fbuf[(size_t)n * 64 + c] + flat_b[c]) * outW[64 + c];
        s += last[(size_t)n * 64 + c] * outW[128 + c];
    }
    out[n] = s;
}

extern "C" void kernel_launch(void* const* d_in, const int* in_sizes, int n_in,
                              void* d_out, int out_size, void* d_ws, size_t ws_size,
                              hipStream_t stream) {
    const float* x    = (const float*)d_in[0];
    const float* flat = (const float*)d_in[1];
    const float* last = (const float*)d_in[2];
    const int*  es1i  = (const int*)d_in[3];
    const int*  ed1i  = (const int*)d_in[4];
    const int*  es2i  = (const int*)d_in[5];
    const int*  ed2i  = (const int*)d_in[6];
    const float* W1s  = (const float*)d_in[7];
    const float* W1d  = (const float*)d_in[8];
    const float* a1s  = (const float*)d_in[9];
    const float* a1d  = (const float*)d_in[10];
    const float* b1   = (const float*)d_in[11];
    const float* W2s  = (const float*)d_in[12];
    const float* W2d  = (const float*)d_in[13];
    const float* a2s  = (const float*)d_in[14];
    const float* a2d  = (const float*)d_in[15];
    const float* b2   = (const float*)d_in[16];
    const float* fW   = (const float*)d_in[17];
    const float* fb   = (const float*)d_in[18];
    const float* oW   = (const float*)d_in[19];
    const float* ob   = (const float*)d_in[20];
    float* out = (float*)d_out;

    float* ws = (float*)d_ws;
    // ---- layout (float-element offsets; proven footprint) ----
    unsigned short* hs1_bf = (unsigned short*)ws;                  // 40,960,000 us
    unsigned short* hd1_bf = (unsigned short*)(ws + 20480000);     //  8,192,000 us
    float* es1f = ws + 24576000;                                   // 640,000
    float* ed1f = ws + 25216000;                                   // 128,000
    float* acc1 = ws + 25344000;                                   // 8,192,000 -> 33,536,000
    unsigned short* wb = (unsigned short*)(ws + 54016000);
    unsigned short* w1s_hi = wb;
    unsigned short* w1s_lo = wb + 131072;
    unsigned short* w1d_hi = wb + 262144;
    unsigned short* w1d_lo = wb + 393216;
    unsigned short* w2s_hi = wb + 524288;
    unsigned short* w2s_lo = wb + 655360;
    unsigned short* w2d_hi = wb + 786432;
    unsigned short* w2d_lo = wb + 917504;
    unsigned short* fw_t3  = wb + 1048576;
    int* ibase   = (int*)(ws + 54816000);
    int* cnt1    = ibase;
    int* cursor1 = ibase + 16000;
    int* cnt2    = ibase + 32000;
    int* cursor2 = ibase + 36096;
    int* start1  = ibase + 40192;
    int* start2  = ibase + 56193;
    int* csr1    = ibase + 60290;
    int* csr2    = ibase + 316290;
    const size_t NEED = ((size_t)54816000 + 381826) * 4;
    if (ws_size < NEED) {
        fprintf(stderr, "kernel_launch: ws_size %zu < needed %zu\n", ws_size, NEED);
        return;
    }
    unsigned short* hs2_bf = (unsigned short*)ws;
    unsigned short* hd2_bf = (unsigned short*)(ws + 2048000);
    float* es2f = ws + 2572288;
    float* ed2f = ws + 2636288;
    float* acc2 = ws + 2652672;
    float* fbuf = ws + 3701248;

    // ---- prep (1 launch) + CSR build (3 launches) ----
    {
        int total = 262144 + 262144 + 8192 + 40192;
        prep_kernel<<<(total + 255) / 256, 256, 0, stream>>>(
            W1s, W1d, w1s_hi, w1s_lo, w1d_hi, w1d_lo,
            W2s, W2d, w2s_hi, w2s_lo, w2d_hi, w2d_lo,
            fW, fw_t3, ibase, 40192);
    }
    hist_dual<<<(E1 + E2 + 255) / 256, 256, 0, stream>>>(ed1i, cnt1, ed2i, cnt2);
    scan_dual<<<2, 1024, 0, stream>>>(cnt1, start1, N2, cnt2, start2, N3);
    fill_dual<<<(E1 + E2 + 255) / 256, 256, 0, stream>>>(
        es1i, ed1i, start1, cursor1, csr1, es2i, ed2i, start2, cursor2, csr2);

    // ---- layer 1: src+dst GEMMs in one grid, fused escore ----
    gemm_fused<<<dim3(2, N1 / 64 + N2 / 64), 256, 0, stream>>>(
        x, w1s_hi, w1s_lo, hs1_bf, a1s, es1f,
        w1d_hi, w1d_lo, hd1_bf, a1d, ed1f,
        N1 / 64, 512, 256, 8);
    gat_agg2<8, true><<<N2 / 4, 256, 0, stream>>>(csr1, start1, hs1_bf, es1f, ed1f, b1, acc1, N2);

    // ---- layer 2: src+dst GEMMs in one grid ----
    gemm_fused<<<dim3(1, N2 / 64 + N3 / 64), 256, 0, stream>>>(
        acc1, w2s_hi, w2s_lo, hs2_bf, a2s, es2f,
        w2d_hi, w2d_lo, hd2_bf, a2d, ed2f,
        N2 / 64, 256, 512, 4);
    gat_agg2<4, false><<<N3 / 4, 256, 0, stream>>>(csr2, start2, hs2_bf, es2f, ed2f, nullptr, acc2, N3);

    // ---- flat MLP + output ----
    gemm_mfma<<<dim3(1, N3 / 64), 256, 0, stream>>>(flat, fw_t3, fbuf, N3, 64, 128);
    final_kernel<<<(N3 + 255) / 256, 256, 0, stream>>>(acc2, b2, fbuf, fb, last, oW, ob, out, N3);
}